// Round 5
// baseline (364.770 us; speedup 1.0000x reference)
//
#include <hip/hip_runtime.h>
#include <hip/hip_bf16.h>

// Problem dims
#define BB 64
#define TT 128
#define FIN 12
#define HH 128

#define LOG2E 1.4426950408889634f
#define TWO_LOG2E 2.8853900817779268f

__device__ __forceinline__ float fexp2(float x) { return __builtin_amdgcn_exp2f(x); }
__device__ __forceinline__ float frcp(float x)  { return __builtin_amdgcn_rcpf(x); }

// tanh(x) = 1 - 2/(1+e^{2x}); correct limits at +/-inf via exp2->{inf,0}
__device__ __forceinline__ float tanh_f(float x) {
  return 1.0f - 2.0f * frcp(1.0f + fexp2(TWO_LOG2E * x));
}
__device__ __forceinline__ float sigm_f(float x) {
  return frcp(1.0f + fexp2(-LOG2E * x));
}

// DPP 8-lane sum (over lane bits 0..2). Pure VALU -- no DS traffic.
template <int CTRL>
__device__ __forceinline__ float dpp_addstage(float v) {
  int s = __builtin_amdgcn_update_dpp(0, __float_as_int(v), CTRL, 0xF, 0xF, true);
  return v + __int_as_float(s);
}
__device__ __forceinline__ float red8(float v) {
  v = dpp_addstage<0xB1>(v);   // quad_perm [1,0,3,2]: partner lane^1
  v = dpp_addstage<0x4E>(v);   // quad_perm [2,3,0,1]: partner lane^2
  v = dpp_addstage<0x141>(v);  // row_half_mirror: partner lane^7 -> 8-lane total
  return v;
}

#define FMA4S(acc, s, v) do { \
  acc.x = fmaf((s), (v).x, acc.x); \
  acc.y = fmaf((s), (v).y, acc.y); \
  acc.z = fmaf((s), (v).z, acc.z); \
  acc.w = fmaf((s), (v).w, acc.w); } while (0)

#define ACC4(hv, wv, a) do { \
  a = fmaf((hv).x, (wv).x, a); a = fmaf((hv).y, (wv).y, a); \
  a = fmaf((hv).z, (wv).z, a); a = fmaf((hv).w, (wv).w, a); } while (0)

// ---------------------------------------------------------------------------
// Shared LSTM phase body (v6 structure, measured 103.5us/phase).
// Layout: thread (i = tid>>3, q = tid&7) owns 4 gate rows of h-index i over
// k-slice [16q,16q+16); h skewed (16-float blocks padded to 20); q==0 lane
// applies activations. 1 barrier/step; zero vm ops in the step loop.
// ---------------------------------------------------------------------------
__device__ __forceinline__ void lstm_phase(
    const float* __restrict__ Wih, const float* __restrict__ Whh,
    const float* __restrict__ bias, float* __restrict__ Hout /* b-offset applied */,
    float* __restrict__ xs, float (*hbuf)[160], float* __restrict__ hist,
    const int tid, const int q, const int i, float& c)
{
  const int xo   = (q < 4) ? 3 * q : 0;
  const float xz = (q < 4) ? 1.0f : 0.0f;

  float4 wg[4][4];
  #pragma unroll
  for (int g = 0; g < 4; ++g)
    #pragma unroll
    for (int j = 0; j < 4; ++j)
      wg[g][j] = *(const float4*)(Whh + ((g * HH + i) * HH) + 16 * q + 4 * j);

  float wx[4][3];
  #pragma unroll
  for (int g = 0; g < 4; ++g)
    #pragma unroll
    for (int j = 0; j < 3; ++j)
      wx[g][j] = Wih[(g * HH + i) * FIN + xo + j] * xz;

  const float bi = bias[i], bf = bias[HH + i], bg = bias[2 * HH + i], bo = bias[3 * HH + i];

  int ts = 0;
  #pragma unroll 1
  for (int half = 0; half < 2; ++half) {
    #pragma unroll 1
    for (int tt = 0; tt < 64; ++tt, ++ts) {
      const int t = half * 64 + tt;
      __syncthreads();  // h(t) ready in hbuf[ts&1]; hist copy reads done
      const float* hb = (const float*)hbuf[ts & 1] + q * 20;
      float4 h0 = *(const float4*)(hb + 0);
      float4 h1 = *(const float4*)(hb + 4);
      float4 h2 = *(const float4*)(hb + 8);
      float4 h3 = *(const float4*)(hb + 12);

      const float* xt = xs + t * FIN + xo;
      float x0 = xt[0], x1 = xt[1], x2 = xt[2];
      float ai = wx[0][0] * x0 + wx[0][1] * x1 + wx[0][2] * x2;
      float af = wx[1][0] * x0 + wx[1][1] * x1 + wx[1][2] * x2;
      float ag = wx[2][0] * x0 + wx[2][1] * x1 + wx[2][2] * x2;
      float ao = wx[3][0] * x0 + wx[3][1] * x1 + wx[3][2] * x2;

      ACC4(h0, wg[0][0], ai); ACC4(h0, wg[1][0], af); ACC4(h0, wg[2][0], ag); ACC4(h0, wg[3][0], ao);
      ACC4(h1, wg[0][1], ai); ACC4(h1, wg[1][1], af); ACC4(h1, wg[2][1], ag); ACC4(h1, wg[3][1], ao);
      ACC4(h2, wg[0][2], ai); ACC4(h2, wg[1][2], af); ACC4(h2, wg[2][2], ag); ACC4(h2, wg[3][2], ao);
      ACC4(h3, wg[0][3], ai); ACC4(h3, wg[1][3], af); ACC4(h3, wg[2][3], ag); ACC4(h3, wg[3][3], ao);

      ai = red8(ai); af = red8(af); ag = red8(ag); ao = red8(ao);

      if (q == 0) {
        float zi = sigm_f(ai + bi);
        float zf = sigm_f(af + bf);
        float zg = tanh_f(ag + bg);
        float zo = sigm_f(ao + bo);
        c = fmaf(zf, c, zi * zg);
        float hn = zo * tanh_f(c);
        hbuf[(ts + 1) & 1][(i >> 4) * 20 + (i & 15)] = hn;
        hist[tt * HH + i] = hn;   // LDS only -- no vm op in the step loop
      }
    }
    __syncthreads();  // hist writes visible
    {
      float4* dst = (float4*)(Hout + (size_t)(half * 64) * HH);
      const float4* src = (const float4*)hist;
      dst[tid]        = src[tid];
      dst[tid + 1024] = src[tid + 1024];
    }
  }
}

// ---------------------------------------------------------------------------
// K1a: encoder LSTM only (64 blocks). Writes encH + final cell state cbuf.
// hT is encH row 127 (no extra write needed).
// ---------------------------------------------------------------------------
__global__ __launch_bounds__(1024, 4) void lstm_enc_kernel(
    const float* __restrict__ x,
    const float* __restrict__ eWih, const float* __restrict__ eWhh, const float* __restrict__ eb,
    float* __restrict__ encH, float* __restrict__ cbuf)
{
  const int b   = blockIdx.x;
  const int tid = threadIdx.x;
  const int q   = tid & 7;
  const int i   = tid >> 3;

  __shared__ __align__(16) float xs[TT * FIN];
  __shared__ __align__(16) float hbuf[2][160];
  __shared__ __align__(16) float hist[64 * HH];

  if (tid < (TT * FIN / 4))
    ((float4*)xs)[tid] = ((const float4*)(x + (size_t)b * TT * FIN))[tid];
  if (tid < 320) ((float*)hbuf)[tid] = 0.0f;
  float c = 0.0f;

  lstm_phase(eWih, eWhh, eb, encH + (size_t)b * TT * HH, xs, hbuf, hist, tid, q, i, c);

  if (q == 0) cbuf[b * HH + i] = c;   // hand cell state to decoder kernel
}

// ---------------------------------------------------------------------------
// K1b: heterogeneous grid (192 blocks x 1024 thr).
//  blocks 0..63:   decoder LSTM (init h,c from encH row 127 / cbuf) -> decH.
//  blocks 64..191: P projection, 64-row tiles: Ep = exp2(2log2e * encH@W2^T)
//                  -> Pbuf.  P depends only on encH, so it runs on the 128
//                  CUs the recurrence leaves idle -- its ~15us disappears
//                  under the decoder's ~103us.
// ---------------------------------------------------------------------------
__global__ __launch_bounds__(1024, 4) void lstm_dec_p_kernel(
    const float* __restrict__ x,
    const float* __restrict__ dWih, const float* __restrict__ dWhh, const float* __restrict__ db,
    const float* __restrict__ attnW,
    const float* __restrict__ encH, const float* __restrict__ cbuf,
    float* __restrict__ decH, float* __restrict__ Pbuf)
{
  __shared__ __align__(16) float smem[12416];   // 48.5 KB, overlaid per path
  const int tid = threadIdx.x;

  if (blockIdx.x < 64) {
    // ---- decoder LSTM ----
    const int b = blockIdx.x;
    const int q = tid & 7;
    const int i = tid >> 3;
    float* xs           = smem;                          // 1536 floats
    float (*hbuf)[160]  = (float(*)[160])(smem + 1536);  // 320 floats
    float* hist         = smem + 1856;                   // 8192 floats

    if (tid < (TT * FIN / 4))
      ((float4*)xs)[tid] = ((const float4*)(x + (size_t)b * TT * FIN))[tid];
    if (tid < 128) {  // h0 = hT = encH row 127, skewed into hbuf[0]
      float hv = encH[((size_t)b * TT + 127) * HH + tid];
      hbuf[0][(tid >> 4) * 20 + (tid & 15)] = hv;
    }
    float c = 0.0f;
    if (q == 0) c = cbuf[b * HH + i];   // c0 = cT

    lstm_phase(dWih, dWhh, db, decH + (size_t)b * TT * HH, xs, hbuf, hist, tid, q, i, c);
  } else {
    // ---- P projection (64-row tile) ----
    const int pb = blockIdx.x - 64;
    const int b  = pb & 63;
    const int r0 = (pb >> 6) * 64;
    float* WT = smem;          // [32][132] padded k-major W2^T quarter, 4224 floats
    float* Xt = smem + 4224;   // [64][128] encH tile, 8192 floats

    const float* X = encH + ((size_t)b * TT + r0) * HH;
    ((float4*)Xt)[tid]        = ((const float4*)X)[tid];
    ((float4*)Xt)[tid + 1024] = ((const float4*)X)[tid + 1024];

    const float* W = attnW + HH;   // W2 = attnW[:, H:2H], row stride 2H
    const int hq = tid & 31, rr = tid >> 5;   // rr 0..31 -> rows 2rr, 2rr+1
    const int h0 = 4 * hq;

    float4 acc0 = make_float4(0.f, 0.f, 0.f, 0.f);
    float4 acc1 = acc0;

    #pragma unroll 1
    for (int kb = 0; kb < 4; ++kb) {
      __syncthreads();
      { // stage 128h x 32k quarter, transposed, padded stride 132
        int h = tid >> 3, koff = (tid & 7) * 4;
        float4 v = *(const float4*)(W + h * 256 + kb * 32 + koff);
        WT[(koff + 0) * 132 + h] = v.x;
        WT[(koff + 1) * 132 + h] = v.y;
        WT[(koff + 2) * 132 + h] = v.z;
        WT[(koff + 3) * 132 + h] = v.w;
      }
      __syncthreads();
      const float* xr0 = Xt + (2 * rr) * 128 + kb * 32;
      const float* xr1 = xr0 + 128;
      #pragma unroll
      for (int k4 = 0; k4 < 32; k4 += 4) {
        float4 xa = *(const float4*)(xr0 + k4);
        float4 xb = *(const float4*)(xr1 + k4);
        float4 w0 = *(const float4*)&WT[(k4 + 0) * 132 + h0];
        float4 w1 = *(const float4*)&WT[(k4 + 1) * 132 + h0];
        float4 w2 = *(const float4*)&WT[(k4 + 2) * 132 + h0];
        float4 w3 = *(const float4*)&WT[(k4 + 3) * 132 + h0];
        FMA4S(acc0, xa.x, w0); FMA4S(acc0, xa.y, w1);
        FMA4S(acc0, xa.z, w2); FMA4S(acc0, xa.w, w3);
        FMA4S(acc1, xb.x, w0); FMA4S(acc1, xb.y, w1);
        FMA4S(acc1, xb.z, w2); FMA4S(acc1, xb.w, w3);
      }
    }
    // store Ep = exp2(2log2e * P) so K3 skips the exp2 (and its 8x per-b redo)
    acc0.x = fexp2(TWO_LOG2E * acc0.x); acc0.y = fexp2(TWO_LOG2E * acc0.y);
    acc0.z = fexp2(TWO_LOG2E * acc0.z); acc0.w = fexp2(TWO_LOG2E * acc0.w);
    acc1.x = fexp2(TWO_LOG2E * acc1.x); acc1.y = fexp2(TWO_LOG2E * acc1.y);
    acc1.z = fexp2(TWO_LOG2E * acc1.z); acc1.w = fexp2(TWO_LOG2E * acc1.w);
    float* O = Pbuf + ((size_t)b * TT + r0) * HH;
    *(float4*)(O + (2 * rr) * 128 + h0)     = acc0;
    *(float4*)(O + (2 * rr + 1) * 128 + h0) = acc1;
  }
}

// ---------------------------------------------------------------------------
// K3 v3: attention + output, with the A projection folded in.
//  - A = dh @ W1^T + attn_b computed in-block from the already-staged dh
//    (W1 from global; the 16-row redundancy is L1-resident).  Removes the
//    old proj_kernel m=0 half and the Abuf global roundtrip.
//  - Pbuf already holds Ep -> staging loop is a pure swizzled transpose.
//  - tanh factorization + AST=132 padding as v2 (energy loop: fma,rcp,fma).
// ---------------------------------------------------------------------------
#define AST 132  // padded row stride for a_lds / sc

__global__ __launch_bounds__(512, 2) void attn_kernel(
    const float* __restrict__ encH, const float* __restrict__ decH,
    const float* __restrict__ Pbuf,
    const float* __restrict__ attnW, const float* __restrict__ attnb,
    const float* __restrict__ vw, const float* __restrict__ outW,
    const float* __restrict__ outb, float* __restrict__ out)
{
  const int b  = blockIdx.x >> 3;
  const int s0 = (blockIdx.x & 7) * 16;
  const int tid = threadIdx.x;

  __shared__ __align__(16) float buf[64 * 128];    // 32 KB: Ep^T-half (swizzled), later encH-half
  __shared__ __align__(16) float a_lds[16 * AST];  // Ea tile, later ctx
  __shared__ __align__(16) float sc[16 * AST];     // scores -> weights
  __shared__ __align__(16) float dh[16 * 128];     // decH tile
  __shared__ __align__(16) float vl[HH];

  ((float4*)dh)[tid] = ((const float4*)(decH + ((size_t)b * TT + s0) * HH))[tid];
  if (tid < 32) ((float4*)vl)[tid] = ((const float4*)vw)[tid];

  const int u  = tid & 31;
  const int sl = tid >> 5;   // 0..15 decoder-step within tile
  const int uq = u & 15;     // t-quad within half
  const int uh = u >> 4;     // 0/1 h-half

  __syncthreads();  // dh staged

  // ---- A = dh @ W1^T + attn_b;  Ea = exp2(2log2e * A) ----
  {
    const int h0 = 4 * u;
    float4 acc = *(const float4*)(attnb + h0);
    const float* drow = dh + sl * 128;
    const float* w0p = attnW + (size_t)(h0 + 0) * 256;
    const float* w1p = attnW + (size_t)(h0 + 1) * 256;
    const float* w2p = attnW + (size_t)(h0 + 2) * 256;
    const float* w3p = attnW + (size_t)(h0 + 3) * 256;
    #pragma unroll 8
    for (int k4 = 0; k4 < 128; k4 += 4) {
      float4 dv = *(const float4*)(drow + k4);
      float4 wa = *(const float4*)(w0p + k4);
      float4 wb = *(const float4*)(w1p + k4);
      float4 wc = *(const float4*)(w2p + k4);
      float4 wd = *(const float4*)(w3p + k4);
      ACC4(dv, wa, acc.x);
      ACC4(dv, wb, acc.y);
      ACC4(dv, wc, acc.z);
      ACC4(dv, wd, acc.w);
    }
    acc.x = fexp2(TWO_LOG2E * acc.x);
    acc.y = fexp2(TWO_LOG2E * acc.y);
    acc.z = fexp2(TWO_LOG2E * acc.z);
    acc.w = fexp2(TWO_LOG2E * acc.w);
    *(float4*)&a_lds[sl * AST + h0] = acc;
  }

  // ---- energies/scores ----
  for (int half = 0; half < 2; ++half) {
    const int tbase = half * 64;
    __syncthreads();  // prev buf use done; also covers a_lds (Ea) writes
    #pragma unroll
    for (int i = 0; i < 4; ++i) {
      int flat = i * 2048 + tid * 4;
      int tp = flat >> 7;        // 0..63
      int h0 = flat & 127;
      float4 v = *(const float4*)(Pbuf + ((size_t)b * TT + tbase + tp) * HH + h0);
      int tq = tp >> 2, tr = tp & 3;
      buf[(h0 + 0) * 64 + 4 * ((tq ^ ((h0 + 0) >> 2)) & 15) + tr] = v.x;
      buf[(h0 + 1) * 64 + 4 * ((tq ^ ((h0 + 1) >> 2)) & 15) + tr] = v.y;
      buf[(h0 + 2) * 64 + 4 * ((tq ^ ((h0 + 2) >> 2)) & 15) + tr] = v.z;
      buf[(h0 + 3) * 64 + 4 * ((tq ^ ((h0 + 3) >> 2)) & 15) + tr] = v.w;
    }
    __syncthreads();
    float4 acc = make_float4(0.f, 0.f, 0.f, 0.f);
    const float* earow = a_lds + sl * AST;
    #pragma unroll 4
    for (int hh = 0; hh < 64; hh += 4) {
      const int h = uh * 64 + hh;
      float4 ea = *(const float4*)&earow[h];
      float4 va = *(const float4*)&vl[h];
      const int xoff = 4 * ((uq ^ ((h >> 2) & 15)) & 15);  // same for h..h+3
      float4 p0 = *(const float4*)&buf[(h + 0) * 64 + xoff];
      float4 p1 = *(const float4*)&buf[(h + 1) * 64 + xoff];
      float4 p2 = *(const float4*)&buf[(h + 2) * 64 + xoff];
      float4 p3 = *(const float4*)&buf[(h + 3) * 64 + xoff];
      acc.x = fmaf(va.x, frcp(fmaf(ea.x, p0.x, 1.f)), acc.x);
      acc.y = fmaf(va.x, frcp(fmaf(ea.x, p0.y, 1.f)), acc.y);
      acc.z = fmaf(va.x, frcp(fmaf(ea.x, p0.z, 1.f)), acc.z);
      acc.w = fmaf(va.x, frcp(fmaf(ea.x, p0.w, 1.f)), acc.w);
      acc.x = fmaf(va.y, frcp(fmaf(ea.y, p1.x, 1.f)), acc.x);
      acc.y = fmaf(va.y, frcp(fmaf(ea.y, p1.y, 1.f)), acc.y);
      acc.z = fmaf(va.y, frcp(fmaf(ea.y, p1.z, 1.f)), acc.z);
      acc.w = fmaf(va.y, frcp(fmaf(ea.y, p1.w, 1.f)), acc.w);
      acc.x = fmaf(va.z, frcp(fmaf(ea.z, p2.x, 1.f)), acc.x);
      acc.y = fmaf(va.z, frcp(fmaf(ea.z, p2.y, 1.f)), acc.y);
      acc.z = fmaf(va.z, frcp(fmaf(ea.z, p2.z, 1.f)), acc.z);
      acc.w = fmaf(va.z, frcp(fmaf(ea.z, p2.w, 1.f)), acc.w);
      acc.x = fmaf(va.w, frcp(fmaf(ea.w, p3.x, 1.f)), acc.x);
      acc.y = fmaf(va.w, frcp(fmaf(ea.w, p3.y, 1.f)), acc.y);
      acc.z = fmaf(va.w, frcp(fmaf(ea.w, p3.z, 1.f)), acc.z);
      acc.w = fmaf(va.w, frcp(fmaf(ea.w, p3.w, 1.f)), acc.w);
    }
    acc.x += __shfl_xor(acc.x, 16, 64);
    acc.y += __shfl_xor(acc.y, 16, 64);
    acc.z += __shfl_xor(acc.z, 16, 64);
    acc.w += __shfl_xor(acc.w, 16, 64);
    if (uh == 0) {
      float4 o;
      o.x = -2.f * acc.x; o.y = -2.f * acc.y;
      o.z = -2.f * acc.z; o.w = -2.f * acc.w;
      *(float4*)&sc[sl * AST + tbase + 4 * uq] = o;
    }
  }
  __syncthreads();

  // ---- softmax over t (per s row; 32 lanes x f4 = 128) ----
  {
    float4 sv = *(const float4*)&sc[sl * AST + 4 * u];
    float mx = fmaxf(fmaxf(sv.x, sv.y), fmaxf(sv.z, sv.w));
    #pragma unroll
    for (int msk = 1; msk <= 16; msk <<= 1) mx = fmaxf(mx, __shfl_xor(mx, msk, 64));
    float4 e;
    e.x = fexp2(LOG2E * (sv.x - mx));
    e.y = fexp2(LOG2E * (sv.y - mx));
    e.z = fexp2(LOG2E * (sv.z - mx));
    e.w = fexp2(LOG2E * (sv.w - mx));
    float sm = (e.x + e.y) + (e.z + e.w);
    #pragma unroll
    for (int msk = 1; msk <= 16; msk <<= 1) sm += __shfl_xor(sm, msk, 64);
    float r = frcp(sm);
    e.x *= r; e.y *= r; e.z *= r; e.w *= r;
    *(float4*)&sc[sl * AST + 4 * u] = e;
  }

  // ---- ctx = w @ encH ----
  float4 ctx = make_float4(0.f, 0.f, 0.f, 0.f);
  const int h0c = 4 * u;
  for (int half = 0; half < 2; ++half) {
    const int tbase = half * 64;
    __syncthreads();  // buf reuse; also orders softmax writes before reads
    #pragma unroll
    for (int i = 0; i < 4; ++i) {
      int flat = i * 2048 + tid * 4;
      int tp = flat >> 7;
      int hh0 = flat & 127;
      *(float4*)&buf[tp * 128 + hh0] =
          *(const float4*)(encH + ((size_t)b * TT + tbase + tp) * HH + hh0);
    }
    __syncthreads();
    const float* wrow = sc + sl * AST + tbase;
    #pragma unroll 8
    for (int tp = 0; tp < 64; ++tp) {
      float wt = wrow[tp];
      float4 e4 = *(const float4*)&buf[tp * 128 + h0c];
      FMA4S(ctx, wt, e4);
    }
  }
  __syncthreads();
  *(float4*)&a_lds[sl * AST + h0c] = ctx;  // overlay Ea tile with ctx
  __syncthreads();

  // ---- out = [decH, ctx] @ outW^T + outb ----
  if (tid < 192) {
    int s = tid / 12, f = tid % 12;
    float acc = outb[f];
    const float4* w4 = (const float4*)(outW + f * 256);
    const float4* d4 = (const float4*)(dh + s * 128);
    const float4* c4 = (const float4*)(a_lds + s * AST);
    #pragma unroll
    for (int k = 0; k < 32; ++k) {
      float4 wv = w4[k], dv = d4[k];
      acc = fmaf(wv.x, dv.x, acc); acc = fmaf(wv.y, dv.y, acc);
      acc = fmaf(wv.z, dv.z, acc); acc = fmaf(wv.w, dv.w, acc);
    }
    #pragma unroll
    for (int k = 0; k < 32; ++k) {
      float4 wv = w4[32 + k], cv = c4[k];
      acc = fmaf(wv.x, cv.x, acc); acc = fmaf(wv.y, cv.y, acc);
      acc = fmaf(wv.z, cv.z, acc); acc = fmaf(wv.w, cv.w, acc);
    }
    out[((size_t)b * TT + s0 + s) * FIN + f] = acc;
  }
}

// ---------------------------------------------------------------------------
extern "C" void kernel_launch(void* const* d_in, const int* in_sizes, int n_in,
                              void* d_out, int out_size, void* d_ws, size_t ws_size,
                              hipStream_t stream)
{
  const float* x     = (const float*)d_in[0];
  const float* eWih  = (const float*)d_in[1];
  const float* eWhh  = (const float*)d_in[2];
  const float* eb    = (const float*)d_in[3];
  const float* dWih  = (const float*)d_in[4];
  const float* dWhh  = (const float*)d_in[5];
  const float* db    = (const float*)d_in[6];
  const float* attnW = (const float*)d_in[7];
  const float* attnb = (const float*)d_in[8];
  const float* vw    = (const float*)d_in[9];
  const float* outW  = (const float*)d_in[10];
  const float* outb  = (const float*)d_in[11];
  float* out = (float*)d_out;

  float* ws   = (float*)d_ws;
  const size_t SEG = (size_t)BB * TT * HH;  // 1,048,576 floats = 4 MB
  float* encH = ws;
  float* decH = ws + SEG;
  float* Pbuf = ws + 2 * SEG;   // holds Ep = exp2(2log2e * P)
  float* cbuf = ws + 3 * SEG;   // 64*128 floats: encoder cell state

  lstm_enc_kernel<<<64, 1024, 0, stream>>>(x, eWih, eWhh, eb, encH, cbuf);
  lstm_dec_p_kernel<<<192, 1024, 0, stream>>>(x, dWih, dWhh, db, attnW, encH, cbuf, decH, Pbuf);
  attn_kernel<<<512, 512, 0, stream>>>(encH, decH, Pbuf, attnW, attnb, vw, outW, outb, out);
}

// Round 6
// 355.693 us; speedup vs baseline: 1.0255x; 1.0255x over previous
//
#include <hip/hip_runtime.h>
#include <hip/hip_bf16.h>

// Problem dims
#define BB 64
#define TT 128
#define FIN 12
#define HH 128

#define LOG2E 1.4426950408889634f
#define TWO_LOG2E 2.8853900817779268f

typedef float f2v __attribute__((ext_vector_type(2)));
union F4 { float4 v; f2v h[2]; };

__device__ __forceinline__ float fexp2(float x) { return __builtin_amdgcn_exp2f(x); }
__device__ __forceinline__ float frcp(float x)  { return __builtin_amdgcn_rcpf(x); }

// tanh(x) = 1 - 2/(1+e^{2x}); correct limits at +/-inf via exp2->{inf,0}
__device__ __forceinline__ float tanh_f(float x) {
  return 1.0f - 2.0f * frcp(1.0f + fexp2(TWO_LOG2E * x));
}
__device__ __forceinline__ float sigm_f(float x) {
  return frcp(1.0f + fexp2(-LOG2E * x));
}

// DPP 8-lane sum (over lane bits 0..2). Pure VALU -- no DS traffic.
template <int CTRL>
__device__ __forceinline__ float dpp_addstage(float v) {
  int s = __builtin_amdgcn_update_dpp(0, __float_as_int(v), CTRL, 0xF, 0xF, true);
  return v + __int_as_float(s);
}
__device__ __forceinline__ float red8(float v) {
  v = dpp_addstage<0xB1>(v);   // quad_perm [1,0,3,2]: partner lane^1
  v = dpp_addstage<0x4E>(v);   // quad_perm [2,3,0,1]: partner lane^2
  v = dpp_addstage<0x141>(v);  // row_half_mirror: partner lane^7 -> 8-lane total
  return v;
}

// packed dual-FMA: acc.{x,y} += hh.{x,y} * ww.{x,y}  (one VALU inst)
#define PKFMA(acc, hh, ww) \
  asm("v_pk_fma_f32 %0, %1, %2, %0" : "+v"(acc) : "v"(hh), "v"(ww))

#define FMA4S(acc, s, v) do { \
  acc.x = fmaf((s), (v).x, acc.x); \
  acc.y = fmaf((s), (v).y, acc.y); \
  acc.z = fmaf((s), (v).z, acc.z); \
  acc.w = fmaf((s), (v).w, acc.w); } while (0)

#define ACC4(hv, wv, a) do { \
  a = fmaf((hv).x, (wv).x, a); a = fmaf((hv).y, (wv).y, a); \
  a = fmaf((hv).z, (wv).z, a); a = fmaf((hv).w, (wv).w, a); } while (0)

// ---------------------------------------------------------------------------
// Shared LSTM phase body (v6 structure + v_pk_fma_f32 inner product).
// Thread (i = tid>>3, q = tid&7) owns 4 gate rows of h-index i over k-slice
// [16q,16q+16).  Packed math halves the dot-product issue count: 32 pk-FMA
// vs 64 scalar FMA per lane per step.  1 barrier/step; zero vm ops in loop.
// ---------------------------------------------------------------------------
__device__ __forceinline__ void lstm_phase(
    const float* __restrict__ Wih, const float* __restrict__ Whh,
    const float* __restrict__ bias, float* __restrict__ Hout /* b-offset applied */,
    float* __restrict__ xs, float (*hbuf)[160], float* __restrict__ hist,
    const int tid, const int q, const int i, float& c)
{
  const int xo   = (q < 4) ? 3 * q : 0;
  const float xz = (q < 4) ? 1.0f : 0.0f;

  F4 wg[4][4];
  #pragma unroll
  for (int g = 0; g < 4; ++g)
    #pragma unroll
    for (int j = 0; j < 4; ++j)
      wg[g][j].v = *(const float4*)(Whh + ((g * HH + i) * HH) + 16 * q + 4 * j);

  float wx[4][3];
  #pragma unroll
  for (int g = 0; g < 4; ++g)
    #pragma unroll
    for (int j = 0; j < 3; ++j)
      wx[g][j] = Wih[(g * HH + i) * FIN + xo + j] * xz;

  const float bi = bias[i], bf = bias[HH + i], bg = bias[2 * HH + i], bo = bias[3 * HH + i];

  int ts = 0;
  #pragma unroll 1
  for (int half = 0; half < 2; ++half) {
    #pragma unroll 1
    for (int tt = 0; tt < 64; ++tt, ++ts) {
      const int t = half * 64 + tt;
      __syncthreads();  // h(t) ready in hbuf[ts&1]; hist copy reads done
      const float* hb = (const float*)hbuf[ts & 1] + q * 20;
      F4 H[4];
      H[0].v = *(const float4*)(hb + 0);
      H[1].v = *(const float4*)(hb + 4);
      H[2].v = *(const float4*)(hb + 8);
      H[3].v = *(const float4*)(hb + 12);

      const float* xt = xs + t * FIN + xo;
      float x0 = xt[0], x1 = xt[1], x2 = xt[2];
      float ai = wx[0][0] * x0 + wx[0][1] * x1 + wx[0][2] * x2;
      float af = wx[1][0] * x0 + wx[1][1] * x1 + wx[1][2] * x2;
      float ag = wx[2][0] * x0 + wx[2][1] * x1 + wx[2][2] * x2;
      float ao = wx[3][0] * x0 + wx[3][1] * x1 + wx[3][2] * x2;

      f2v A0 = {0.f, 0.f}, A1 = {0.f, 0.f}, A2 = {0.f, 0.f}, A3 = {0.f, 0.f};
      #pragma unroll
      for (int j = 0; j < 4; ++j) {
        PKFMA(A0, H[j].h[0], wg[0][j].h[0]); PKFMA(A0, H[j].h[1], wg[0][j].h[1]);
        PKFMA(A1, H[j].h[0], wg[1][j].h[0]); PKFMA(A1, H[j].h[1], wg[1][j].h[1]);
        PKFMA(A2, H[j].h[0], wg[2][j].h[0]); PKFMA(A2, H[j].h[1], wg[2][j].h[1]);
        PKFMA(A3, H[j].h[0], wg[3][j].h[0]); PKFMA(A3, H[j].h[1], wg[3][j].h[1]);
      }
      ai += A0.x + A0.y; af += A1.x + A1.y;
      ag += A2.x + A2.y; ao += A3.x + A3.y;

      ai = red8(ai); af = red8(af); ag = red8(ag); ao = red8(ao);

      if (q == 0) {
        float zi = sigm_f(ai + bi);
        float zf = sigm_f(af + bf);
        float zg = tanh_f(ag + bg);
        float zo = sigm_f(ao + bo);
        c = fmaf(zf, c, zi * zg);
        float hn = zo * tanh_f(c);
        hbuf[(ts + 1) & 1][(i >> 4) * 20 + (i & 15)] = hn;
        hist[tt * HH + i] = hn;   // LDS only -- no vm op in the step loop
      }
    }
    __syncthreads();  // hist writes visible
    {
      float4* dst = (float4*)(Hout + (size_t)(half * 64) * HH);
      const float4* src = (const float4*)hist;
      dst[tid]        = src[tid];
      dst[tid + 1024] = src[tid + 1024];
    }
  }
}

// ---------------------------------------------------------------------------
// K1a: encoder LSTM (64 blocks) -> encH.  Final cell state cT is stashed in
// decH row 0 of batch b (read by the decoder before its first overwrite),
// final hT is encH row 127 -- no extra workspace segment needed.
// ---------------------------------------------------------------------------
__global__ __launch_bounds__(1024, 4) void lstm_enc_kernel(
    const float* __restrict__ x,
    const float* __restrict__ eWih, const float* __restrict__ eWhh, const float* __restrict__ eb,
    float* __restrict__ encH, float* __restrict__ decH)
{
  const int b   = blockIdx.x;
  const int tid = threadIdx.x;
  const int q   = tid & 7;
  const int i   = tid >> 3;

  __shared__ __align__(16) float xs[TT * FIN];
  __shared__ __align__(16) float hbuf[2][160];
  __shared__ __align__(16) float hist[64 * HH];

  if (tid < (TT * FIN / 4))
    ((float4*)xs)[tid] = ((const float4*)(x + (size_t)b * TT * FIN))[tid];
  if (tid < 320) ((float*)hbuf)[tid] = 0.0f;
  float c = 0.0f;

  lstm_phase(eWih, eWhh, eb, encH + (size_t)b * TT * HH, xs, hbuf, hist, tid, q, i, c);

  if (q == 0) decH[(size_t)b * TT * HH + i] = c;   // cT handoff (row 0, pre-overwrite)
}

// ---------------------------------------------------------------------------
// K1b: heterogeneous grid (192 blocks x 1024 thr).
//  blocks 0..63:   decoder LSTM (h0 = encH row 127, c0 = decH row 0) -> decH.
//  blocks 64..191: Ep = exp2(2log2e * encH@W2^T) -> Pbuf (hidden under dec).
// ---------------------------------------------------------------------------
__global__ __launch_bounds__(1024, 4) void lstm_dec_p_kernel(
    const float* __restrict__ x,
    const float* __restrict__ dWih, const float* __restrict__ dWhh, const float* __restrict__ db,
    const float* __restrict__ attnW,
    const float* __restrict__ encH,
    float* __restrict__ decH, float* __restrict__ Pbuf)
{
  __shared__ __align__(16) float smem[12416];   // 48.5 KB, overlaid per path
  const int tid = threadIdx.x;

  if (blockIdx.x < 64) {
    // ---- decoder LSTM ----
    const int b = blockIdx.x;
    const int q = tid & 7;
    const int i = tid >> 3;
    float* xs           = smem;                          // 1536 floats
    float (*hbuf)[160]  = (float(*)[160])(smem + 1536);  // 320 floats
    float* hist         = smem + 1856;                   // 8192 floats

    if (tid < (TT * FIN / 4))
      ((float4*)xs)[tid] = ((const float4*)(x + (size_t)b * TT * FIN))[tid];
    if (tid < 128) {  // h0 = hT = encH row 127, skewed into hbuf[0]
      float hv = encH[((size_t)b * TT + 127) * HH + tid];
      hbuf[0][(tid >> 4) * 20 + (tid & 15)] = hv;
    }
    float c = 0.0f;
    if (q == 0) c = decH[(size_t)b * TT * HH + i];   // c0 = cT (stashed by enc)

    lstm_phase(dWih, dWhh, db, decH + (size_t)b * TT * HH, xs, hbuf, hist, tid, q, i, c);
  } else {
    // ---- P projection (64-row tile) ----
    const int pb = blockIdx.x - 64;
    const int b  = pb & 63;
    const int r0 = (pb >> 6) * 64;
    float* WT = smem;          // [32][132] padded k-major W2^T quarter, 4224 floats
    float* Xt = smem + 4224;   // [64][128] encH tile, 8192 floats

    const float* X = encH + ((size_t)b * TT + r0) * HH;
    ((float4*)Xt)[tid]        = ((const float4*)X)[tid];
    ((float4*)Xt)[tid + 1024] = ((const float4*)X)[tid + 1024];

    const float* W = attnW + HH;   // W2 = attnW[:, H:2H], row stride 2H
    const int hq = tid & 31, rr = tid >> 5;   // rr 0..31 -> rows 2rr, 2rr+1
    const int h0 = 4 * hq;

    float4 acc0 = make_float4(0.f, 0.f, 0.f, 0.f);
    float4 acc1 = acc0;

    #pragma unroll 1
    for (int kb = 0; kb < 4; ++kb) {
      __syncthreads();
      { // stage 128h x 32k quarter, transposed, padded stride 132
        int h = tid >> 3, koff = (tid & 7) * 4;
        float4 v = *(const float4*)(W + h * 256 + kb * 32 + koff);
        WT[(koff + 0) * 132 + h] = v.x;
        WT[(koff + 1) * 132 + h] = v.y;
        WT[(koff + 2) * 132 + h] = v.z;
        WT[(koff + 3) * 132 + h] = v.w;
      }
      __syncthreads();
      const float* xr0 = Xt + (2 * rr) * 128 + kb * 32;
      const float* xr1 = xr0 + 128;
      #pragma unroll
      for (int k4 = 0; k4 < 32; k4 += 4) {
        float4 xa = *(const float4*)(xr0 + k4);
        float4 xb = *(const float4*)(xr1 + k4);
        float4 w0 = *(const float4*)&WT[(k4 + 0) * 132 + h0];
        float4 w1 = *(const float4*)&WT[(k4 + 1) * 132 + h0];
        float4 w2 = *(const float4*)&WT[(k4 + 2) * 132 + h0];
        float4 w3 = *(const float4*)&WT[(k4 + 3) * 132 + h0];
        FMA4S(acc0, xa.x, w0); FMA4S(acc0, xa.y, w1);
        FMA4S(acc0, xa.z, w2); FMA4S(acc0, xa.w, w3);
        FMA4S(acc1, xb.x, w0); FMA4S(acc1, xb.y, w1);
        FMA4S(acc1, xb.z, w2); FMA4S(acc1, xb.w, w3);
      }
    }
    acc0.x = fexp2(TWO_LOG2E * acc0.x); acc0.y = fexp2(TWO_LOG2E * acc0.y);
    acc0.z = fexp2(TWO_LOG2E * acc0.z); acc0.w = fexp2(TWO_LOG2E * acc0.w);
    acc1.x = fexp2(TWO_LOG2E * acc1.x); acc1.y = fexp2(TWO_LOG2E * acc1.y);
    acc1.z = fexp2(TWO_LOG2E * acc1.z); acc1.w = fexp2(TWO_LOG2E * acc1.w);
    float* O = Pbuf + ((size_t)b * TT + r0) * HH;
    *(float4*)(O + (2 * rr) * 128 + h0)     = acc0;
    *(float4*)(O + (2 * rr + 1) * 128 + h0) = acc1;
  }
}

// ---------------------------------------------------------------------------
// K2: Ea[b,s,h] = exp2(2log2e * (decH[b,s,:]·W1[h,:] + attn_b[h])) -> Abuf.
// Round-4 proj structure (m=0 half) verbatim: LDS-staged W^T, coalesced.
// grid 512 = (8 row-tiles x 64 b), 256 threads.
// ---------------------------------------------------------------------------
__global__ __launch_bounds__(256, 2) void projA_kernel(
    const float* __restrict__ decH, const float* __restrict__ attnW,
    const float* __restrict__ attnb, float* __restrict__ Abuf)
{
  const int b  = blockIdx.x & 63;
  const int r0 = (blockIdx.x >> 6) * 16;
  const int tid = threadIdx.x;

  __shared__ __align__(16) float WT[64 * 128];  // 32 KB: W1^T for a k-half
  __shared__ __align__(16) float Xt[16 * 128];  // 8 KB

  const float* X = decH + ((size_t)b * TT + r0) * HH;
  const float* W = attnW;   // W1 = attnW[:, :H], row stride 2H

  ((float4*)Xt)[tid]       = ((const float4*)X)[tid];
  ((float4*)Xt)[256 + tid] = ((const float4*)X)[256 + tid];

  const int hq = tid & 31, rr = tid >> 5;
  const int h0 = 4 * hq;

  float4 acc0 = *(const float4*)(attnb + h0);
  float4 acc1 = acc0;

  for (int kb = 0; kb < 2; ++kb) {
    __syncthreads();  // protect WT overwrite
    {
      int h = tid >> 1, koff = (tid & 1) * 32;
      #pragma unroll
      for (int j = 0; j < 8; ++j) {
        float4 v = *(const float4*)(W + h * 256 + kb * 64 + koff + 4 * j);
        int kp = koff + 4 * j;
        WT[(kp + 0) * 128 + h] = v.x;
        WT[(kp + 1) * 128 + h] = v.y;
        WT[(kp + 2) * 128 + h] = v.z;
        WT[(kp + 3) * 128 + h] = v.w;
      }
    }
    __syncthreads();
    const float* xr0 = Xt + (2 * rr) * 128 + kb * 64;
    const float* xr1 = xr0 + 128;
    #pragma unroll
    for (int k4 = 0; k4 < 64; k4 += 4) {
      float4 xa = *(const float4*)(xr0 + k4);
      float4 xb = *(const float4*)(xr1 + k4);
      float4 w0 = *(const float4*)&WT[(k4 + 0) * 128 + h0];
      float4 w1 = *(const float4*)&WT[(k4 + 1) * 128 + h0];
      float4 w2 = *(const float4*)&WT[(k4 + 2) * 128 + h0];
      float4 w3 = *(const float4*)&WT[(k4 + 3) * 128 + h0];
      FMA4S(acc0, xa.x, w0); FMA4S(acc0, xa.y, w1);
      FMA4S(acc0, xa.z, w2); FMA4S(acc0, xa.w, w3);
      FMA4S(acc1, xb.x, w0); FMA4S(acc1, xb.y, w1);
      FMA4S(acc1, xb.z, w2); FMA4S(acc1, xb.w, w3);
    }
  }
  acc0.x = fexp2(TWO_LOG2E * acc0.x); acc0.y = fexp2(TWO_LOG2E * acc0.y);
  acc0.z = fexp2(TWO_LOG2E * acc0.z); acc0.w = fexp2(TWO_LOG2E * acc0.w);
  acc1.x = fexp2(TWO_LOG2E * acc1.x); acc1.y = fexp2(TWO_LOG2E * acc1.y);
  acc1.z = fexp2(TWO_LOG2E * acc1.z); acc1.w = fexp2(TWO_LOG2E * acc1.w);
  float* O = Abuf + ((size_t)b * TT + r0) * HH;
  *(float4*)(O + (2 * rr) * 128 + h0)     = acc0;
  *(float4*)(O + (2 * rr + 1) * 128 + h0) = acc1;
}

// ---------------------------------------------------------------------------
// K3 v4: attention + output.  Ea and Ep both precomputed (Abuf/Pbuf) ->
// zero exp2 in staging; energy loop is {fma, rcp, fma}; AST=132 padding.
// ---------------------------------------------------------------------------
#define AST 132  // padded row stride for a_lds / sc

__global__ __launch_bounds__(512, 2) void attn_kernel(
    const float* __restrict__ encH, const float* __restrict__ decH,
    const float* __restrict__ Pbuf, const float* __restrict__ Abuf,
    const float* __restrict__ vw, const float* __restrict__ outW,
    const float* __restrict__ outb, float* __restrict__ out)
{
  const int b  = blockIdx.x >> 3;
  const int s0 = (blockIdx.x & 7) * 16;
  const int tid = threadIdx.x;

  __shared__ __align__(16) float buf[64 * 128];    // 32 KB: Ep^T-half (swizzled), later encH-half
  __shared__ __align__(16) float a_lds[16 * AST];  // Ea tile, later ctx
  __shared__ __align__(16) float sc[16 * AST];     // scores -> weights
  __shared__ __align__(16) float dh[16 * 128];     // decH tile
  __shared__ __align__(16) float vl[HH];

  ((float4*)dh)[tid] = ((const float4*)(decH + ((size_t)b * TT + s0) * HH))[tid];
  if (tid < 32) ((float4*)vl)[tid] = ((const float4*)vw)[tid];
  {
    // Ea tile into padded a_lds (already exp'd by projA)
    int r = tid >> 5, c4 = (tid & 31) * 4;
    float4 av = *(const float4*)(Abuf + ((size_t)b * TT + s0 + r) * HH + c4);
    *(float4*)&a_lds[r * AST + c4] = av;
  }

  const int u  = tid & 31;
  const int sl = tid >> 5;   // 0..15 decoder-step within tile
  const int uq = u & 15;     // t-quad within half
  const int uh = u >> 4;     // 0/1 h-half

  // ---- energies/scores ----
  for (int half = 0; half < 2; ++half) {
    const int tbase = half * 64;
    __syncthreads();  // prev buf use done; also covers initial staging
    #pragma unroll
    for (int i = 0; i < 4; ++i) {
      int flat = i * 2048 + tid * 4;
      int tp = flat >> 7;        // 0..63
      int h0 = flat & 127;
      float4 v = *(const float4*)(Pbuf + ((size_t)b * TT + tbase + tp) * HH + h0);
      int tq = tp >> 2, tr = tp & 3;
      buf[(h0 + 0) * 64 + 4 * ((tq ^ ((h0 + 0) >> 2)) & 15) + tr] = v.x;
      buf[(h0 + 1) * 64 + 4 * ((tq ^ ((h0 + 1) >> 2)) & 15) + tr] = v.y;
      buf[(h0 + 2) * 64 + 4 * ((tq ^ ((h0 + 2) >> 2)) & 15) + tr] = v.z;
      buf[(h0 + 3) * 64 + 4 * ((tq ^ ((h0 + 3) >> 2)) & 15) + tr] = v.w;
    }
    __syncthreads();
    float4 acc = make_float4(0.f, 0.f, 0.f, 0.f);
    const float* earow = a_lds + sl * AST;
    #pragma unroll 4
    for (int hh = 0; hh < 64; hh += 4) {
      const int h = uh * 64 + hh;
      float4 ea = *(const float4*)&earow[h];
      float4 va = *(const float4*)&vl[h];
      const int xoff = 4 * ((uq ^ ((h >> 2) & 15)) & 15);  // same for h..h+3
      float4 p0 = *(const float4*)&buf[(h + 0) * 64 + xoff];
      float4 p1 = *(const float4*)&buf[(h + 1) * 64 + xoff];
      float4 p2 = *(const float4*)&buf[(h + 2) * 64 + xoff];
      float4 p3 = *(const float4*)&buf[(h + 3) * 64 + xoff];
      acc.x = fmaf(va.x, frcp(fmaf(ea.x, p0.x, 1.f)), acc.x);
      acc.y = fmaf(va.x, frcp(fmaf(ea.x, p0.y, 1.f)), acc.y);
      acc.z = fmaf(va.x, frcp(fmaf(ea.x, p0.z, 1.f)), acc.z);
      acc.w = fmaf(va.x, frcp(fmaf(ea.x, p0.w, 1.f)), acc.w);
      acc.x = fmaf(va.y, frcp(fmaf(ea.y, p1.x, 1.f)), acc.x);
      acc.y = fmaf(va.y, frcp(fmaf(ea.y, p1.y, 1.f)), acc.y);
      acc.z = fmaf(va.y, frcp(fmaf(ea.y, p1.z, 1.f)), acc.z);
      acc.w = fmaf(va.y, frcp(fmaf(ea.y, p1.w, 1.f)), acc.w);
      acc.x = fmaf(va.z, frcp(fmaf(ea.z, p2.x, 1.f)), acc.x);
      acc.y = fmaf(va.z, frcp(fmaf(ea.z, p2.y, 1.f)), acc.y);
      acc.z = fmaf(va.z, frcp(fmaf(ea.z, p2.z, 1.f)), acc.z);
      acc.w = fmaf(va.z, frcp(fmaf(ea.z, p2.w, 1.f)), acc.w);
      acc.x = fmaf(va.w, frcp(fmaf(ea.w, p3.x, 1.f)), acc.x);
      acc.y = fmaf(va.w, frcp(fmaf(ea.w, p3.y, 1.f)), acc.y);
      acc.z = fmaf(va.w, frcp(fmaf(ea.w, p3.z, 1.f)), acc.z);
      acc.w = fmaf(va.w, frcp(fmaf(ea.w, p3.w, 1.f)), acc.w);
    }
    acc.x += __shfl_xor(acc.x, 16, 64);
    acc.y += __shfl_xor(acc.y, 16, 64);
    acc.z += __shfl_xor(acc.z, 16, 64);
    acc.w += __shfl_xor(acc.w, 16, 64);
    if (uh == 0) {
      float4 o;
      o.x = -2.f * acc.x; o.y = -2.f * acc.y;
      o.z = -2.f * acc.z; o.w = -2.f * acc.w;
      *(float4*)&sc[sl * AST + tbase + 4 * uq] = o;
    }
  }
  __syncthreads();

  // ---- softmax over t (per s row; 32 lanes x f4 = 128) ----
  {
    float4 sv = *(const float4*)&sc[sl * AST + 4 * u];
    float mx = fmaxf(fmaxf(sv.x, sv.y), fmaxf(sv.z, sv.w));
    #pragma unroll
    for (int msk = 1; msk <= 16; msk <<= 1) mx = fmaxf(mx, __shfl_xor(mx, msk, 64));
    float4 e;
    e.x = fexp2(LOG2E * (sv.x - mx));
    e.y = fexp2(LOG2E * (sv.y - mx));
    e.z = fexp2(LOG2E * (sv.z - mx));
    e.w = fexp2(LOG2E * (sv.w - mx));
    float sm = (e.x + e.y) + (e.z + e.w);
    #pragma unroll
    for (int msk = 1; msk <= 16; msk <<= 1) sm += __shfl_xor(sm, msk, 64);
    float r = frcp(sm);
    e.x *= r; e.y *= r; e.z *= r; e.w *= r;
    *(float4*)&sc[sl * AST + 4 * u] = e;
  }

  // ---- ctx = w @ encH ----
  float4 ctx = make_float4(0.f, 0.f, 0.f, 0.f);
  const int h0c = 4 * u;
  for (int half = 0; half < 2; ++half) {
    const int tbase = half * 64;
    __syncthreads();  // buf reuse; also orders softmax writes before reads
    #pragma unroll
    for (int i = 0; i < 4; ++i) {
      int flat = i * 2048 + tid * 4;
      int tp = flat >> 7;
      int hh0 = flat & 127;
      *(float4*)&buf[tp * 128 + hh0] =
          *(const float4*)(encH + ((size_t)b * TT + tbase + tp) * HH + hh0);
    }
    __syncthreads();
    const float* wrow = sc + sl * AST + tbase;
    #pragma unroll 8
    for (int tp = 0; tp < 64; ++tp) {
      float wt = wrow[tp];
      float4 e4 = *(const float4*)&buf[tp * 128 + h0c];
      FMA4S(ctx, wt, e4);
    }
  }
  __syncthreads();
  *(float4*)&a_lds[sl * AST + h0c] = ctx;  // overlay Ea tile with ctx
  __syncthreads();

  // ---- out = [decH, ctx] @ outW^T + outb ----
  if (tid < 192) {
    int s = tid / 12, f = tid % 12;
    float acc = outb[f];
    const float4* w4 = (const float4*)(outW + f * 256);
    const float4* d4 = (const float4*)(dh + s * 128);
    const float4* c4 = (const float4*)(a_lds + s * AST);
    #pragma unroll
    for (int k = 0; k < 32; ++k) {
      float4 wv = w4[k], dv = d4[k];
      acc = fmaf(wv.x, dv.x, acc); acc = fmaf(wv.y, dv.y, acc);
      acc = fmaf(wv.z, dv.z, acc); acc = fmaf(wv.w, dv.w, acc);
    }
    #pragma unroll
    for (int k = 0; k < 32; ++k) {
      float4 wv = w4[32 + k], cv = c4[k];
      acc = fmaf(wv.x, cv.x, acc); acc = fmaf(wv.y, cv.y, acc);
      acc = fmaf(wv.z, cv.z, acc); acc = fmaf(wv.w, cv.w, acc);
    }
    out[((size_t)b * TT + s0 + s) * FIN + f] = acc;
  }
}

// ---------------------------------------------------------------------------
extern "C" void kernel_launch(void* const* d_in, const int* in_sizes, int n_in,
                              void* d_out, int out_size, void* d_ws, size_t ws_size,
                              hipStream_t stream)
{
  const float* x     = (const float*)d_in[0];
  const float* eWih  = (const float*)d_in[1];
  const float* eWhh  = (const float*)d_in[2];
  const float* eb    = (const float*)d_in[3];
  const float* dWih  = (const float*)d_in[4];
  const float* dWhh  = (const float*)d_in[5];
  const float* db    = (const float*)d_in[6];
  const float* attnW = (const float*)d_in[7];
  const float* attnb = (const float*)d_in[8];
  const float* vw    = (const float*)d_in[9];
  const float* outW  = (const float*)d_in[10];
  const float* outb  = (const float*)d_in[11];
  float* out = (float*)d_out;

  float* ws   = (float*)d_ws;
  const size_t SEG = (size_t)BB * TT * HH;  // 1,048,576 floats = 4 MB
  float* encH = ws;
  float* decH = ws + SEG;
  float* Pbuf = ws + 2 * SEG;   // Ep = exp2(2log2e * P)
  float* Abuf = ws + 3 * SEG;   // Ea = exp2(2log2e * A)

  lstm_enc_kernel<<<64, 1024, 0, stream>>>(x, eWih, eWhh, eb, encH, decH);
  lstm_dec_p_kernel<<<192, 1024, 0, stream>>>(x, dWih, dWhh, db, attnW, encH, decH, Pbuf);
  projA_kernel<<<512, 256, 0, stream>>>(decH, attnW, attnb, Abuf);
  attn_kernel<<<512, 512, 0, stream>>>(encH, decH, Pbuf, Abuf, vw, outW, outb, out);
}

// Round 7
// 326.437 us; speedup vs baseline: 1.1174x; 1.0896x over previous
//
#include <hip/hip_runtime.h>
#include <hip/hip_bf16.h>

// Problem dims
#define BB 64
#define TT 128
#define FIN 12
#define HH 128

#define LOG2E 1.4426950408889634f
#define TWO_LOG2E 2.8853900817779268f

__device__ __forceinline__ float fexp2(float x) { return __builtin_amdgcn_exp2f(x); }
__device__ __forceinline__ float frcp(float x)  { return __builtin_amdgcn_rcpf(x); }

// tanh(x) = 1 - 2/(1+e^{2x}); correct limits at +/-inf via exp2->{inf,0}
__device__ __forceinline__ float tanh_f(float x) {
  return 1.0f - 2.0f * frcp(1.0f + fexp2(TWO_LOG2E * x));
}
__device__ __forceinline__ float sigm_f(float x) {
  return frcp(1.0f + fexp2(-LOG2E * x));
}

// DPP 8-lane sum (over lane bits 0..2). Pure VALU -- no DS traffic.
template <int CTRL>
__device__ __forceinline__ float dpp_addstage(float v) {
  int s = __builtin_amdgcn_update_dpp(0, __float_as_int(v), CTRL, 0xF, 0xF, true);
  return v + __int_as_float(s);
}
__device__ __forceinline__ float red8(float v) {
  v = dpp_addstage<0xB1>(v);   // quad_perm [1,0,3,2]: partner lane^1
  v = dpp_addstage<0x4E>(v);   // quad_perm [2,3,0,1]: partner lane^2
  v = dpp_addstage<0x141>(v);  // row_half_mirror: partner lane^7 -> 8-lane total
  return v;
}

#define FMA4S(acc, s, v) do { \
  acc.x = fmaf((s), (v).x, acc.x); \
  acc.y = fmaf((s), (v).y, acc.y); \
  acc.z = fmaf((s), (v).z, acc.z); \
  acc.w = fmaf((s), (v).w, acc.w); } while (0)

#define ACC4(hv, wv, a) do { \
  a = fmaf((hv).x, (wv).x, a); a = fmaf((hv).y, (wv).y, a); \
  a = fmaf((hv).z, (wv).z, a); a = fmaf((hv).w, (wv).w, a); } while (0)

// ---------------------------------------------------------------------------
// Shared LSTM phase body -- v6 SCALAR structure (measured 107.6/108.2 us).
// PKFMA experiment (round 6) regressed to 125us: inline-asm chains blocked
// the scheduler's load/FMA interleave.  Scalar ACC4 is the proven form.
// ---------------------------------------------------------------------------
__device__ __forceinline__ void lstm_phase(
    const float* __restrict__ Wih, const float* __restrict__ Whh,
    const float* __restrict__ bias, float* __restrict__ Hout /* b-offset applied */,
    float* __restrict__ xs, float (*hbuf)[160], float* __restrict__ hist,
    const int tid, const int q, const int i, float& c)
{
  const int xo   = (q < 4) ? 3 * q : 0;
  const float xz = (q < 4) ? 1.0f : 0.0f;

  float4 wg[4][4];
  #pragma unroll
  for (int g = 0; g < 4; ++g)
    #pragma unroll
    for (int j = 0; j < 4; ++j)
      wg[g][j] = *(const float4*)(Whh + ((g * HH + i) * HH) + 16 * q + 4 * j);

  float wx[4][3];
  #pragma unroll
  for (int g = 0; g < 4; ++g)
    #pragma unroll
    for (int j = 0; j < 3; ++j)
      wx[g][j] = Wih[(g * HH + i) * FIN + xo + j] * xz;

  const float bi = bias[i], bf = bias[HH + i], bg = bias[2 * HH + i], bo = bias[3 * HH + i];

  int ts = 0;
  #pragma unroll 1
  for (int half = 0; half < 2; ++half) {
    #pragma unroll 1
    for (int tt = 0; tt < 64; ++tt, ++ts) {
      const int t = half * 64 + tt;
      __syncthreads();  // h(t) ready in hbuf[ts&1]; hist copy reads done
      const float* hb = (const float*)hbuf[ts & 1] + q * 20;
      float4 h0 = *(const float4*)(hb + 0);
      float4 h1 = *(const float4*)(hb + 4);
      float4 h2 = *(const float4*)(hb + 8);
      float4 h3 = *(const float4*)(hb + 12);

      const float* xt = xs + t * FIN + xo;
      float x0 = xt[0], x1 = xt[1], x2 = xt[2];
      float ai = wx[0][0] * x0 + wx[0][1] * x1 + wx[0][2] * x2;
      float af = wx[1][0] * x0 + wx[1][1] * x1 + wx[1][2] * x2;
      float ag = wx[2][0] * x0 + wx[2][1] * x1 + wx[2][2] * x2;
      float ao = wx[3][0] * x0 + wx[3][1] * x1 + wx[3][2] * x2;

      ACC4(h0, wg[0][0], ai); ACC4(h0, wg[1][0], af); ACC4(h0, wg[2][0], ag); ACC4(h0, wg[3][0], ao);
      ACC4(h1, wg[0][1], ai); ACC4(h1, wg[1][1], af); ACC4(h1, wg[2][1], ag); ACC4(h1, wg[3][1], ao);
      ACC4(h2, wg[0][2], ai); ACC4(h2, wg[1][2], af); ACC4(h2, wg[2][2], ag); ACC4(h2, wg[3][2], ao);
      ACC4(h3, wg[0][3], ai); ACC4(h3, wg[1][3], af); ACC4(h3, wg[2][3], ag); ACC4(h3, wg[3][3], ao);

      ai = red8(ai); af = red8(af); ag = red8(ag); ao = red8(ao);

      if (q == 0) {
        float zi = sigm_f(ai + bi);
        float zf = sigm_f(af + bf);
        float zg = tanh_f(ag + bg);
        float zo = sigm_f(ao + bo);
        c = fmaf(zf, c, zi * zg);
        float hn = zo * tanh_f(c);
        hbuf[(ts + 1) & 1][(i >> 4) * 20 + (i & 15)] = hn;
        hist[tt * HH + i] = hn;   // LDS only -- no vm op in the step loop
      }
    }
    __syncthreads();  // hist writes visible
    {
      float4* dst = (float4*)(Hout + (size_t)(half * 64) * HH);
      const float4* src = (const float4*)hist;
      dst[tid]        = src[tid];
      dst[tid + 1024] = src[tid + 1024];
    }
  }
}

// ---------------------------------------------------------------------------
// K1a: encoder LSTM (64 blocks) -> encH.  cT stashed in decH row 0 (read by
// decoder before first overwrite); hT is encH row 127.
// ---------------------------------------------------------------------------
__global__ __launch_bounds__(1024, 4) void lstm_enc_kernel(
    const float* __restrict__ x,
    const float* __restrict__ eWih, const float* __restrict__ eWhh, const float* __restrict__ eb,
    float* __restrict__ encH, float* __restrict__ decH)
{
  const int b   = blockIdx.x;
  const int tid = threadIdx.x;
  const int q   = tid & 7;
  const int i   = tid >> 3;

  __shared__ __align__(16) float xs[TT * FIN];
  __shared__ __align__(16) float hbuf[2][160];
  __shared__ __align__(16) float hist[64 * HH];

  if (tid < (TT * FIN / 4))
    ((float4*)xs)[tid] = ((const float4*)(x + (size_t)b * TT * FIN))[tid];
  if (tid < 320) ((float*)hbuf)[tid] = 0.0f;
  float c = 0.0f;

  lstm_phase(eWih, eWhh, eb, encH + (size_t)b * TT * HH, xs, hbuf, hist, tid, q, i, c);

  if (q == 0) decH[(size_t)b * TT * HH + i] = c;   // cT handoff (row 0, pre-overwrite)
}

// ---------------------------------------------------------------------------
// K1b: heterogeneous grid (192 blocks x 1024 thr).
//  blocks 0..63:   decoder LSTM (h0 = encH row 127, c0 = decH row 0) -> decH.
//  blocks 64..191: Ep = exp2(2log2e * encH@W2^T) -> Pbuf (hidden under dec).
// ---------------------------------------------------------------------------
__global__ __launch_bounds__(1024, 4) void lstm_dec_p_kernel(
    const float* __restrict__ x,
    const float* __restrict__ dWih, const float* __restrict__ dWhh, const float* __restrict__ db,
    const float* __restrict__ attnW,
    const float* __restrict__ encH,
    float* __restrict__ decH, float* __restrict__ Pbuf)
{
  __shared__ __align__(16) float smem[12416];   // 48.5 KB, overlaid per path
  const int tid = threadIdx.x;

  if (blockIdx.x < 64) {
    // ---- decoder LSTM ----
    const int b = blockIdx.x;
    const int q = tid & 7;
    const int i = tid >> 3;
    float* xs           = smem;                          // 1536 floats
    float (*hbuf)[160]  = (float(*)[160])(smem + 1536);  // 320 floats
    float* hist         = smem + 1856;                   // 8192 floats

    if (tid < (TT * FIN / 4))
      ((float4*)xs)[tid] = ((const float4*)(x + (size_t)b * TT * FIN))[tid];
    if (tid < 128) {  // h0 = hT = encH row 127, skewed into hbuf[0]
      float hv = encH[((size_t)b * TT + 127) * HH + tid];
      hbuf[0][(tid >> 4) * 20 + (tid & 15)] = hv;
    }
    float c = 0.0f;
    if (q == 0) c = decH[(size_t)b * TT * HH + i];   // c0 = cT (stashed by enc)

    lstm_phase(dWih, dWhh, db, decH + (size_t)b * TT * HH, xs, hbuf, hist, tid, q, i, c);
  } else {
    // ---- P projection (64-row tile) ----
    const int pb = blockIdx.x - 64;
    const int b  = pb & 63;
    const int r0 = (pb >> 6) * 64;
    float* WT = smem;          // [32][132] padded k-major W2^T quarter, 4224 floats
    float* Xt = smem + 4224;   // [64][128] encH tile, 8192 floats

    const float* X = encH + ((size_t)b * TT + r0) * HH;
    ((float4*)Xt)[tid]        = ((const float4*)X)[tid];
    ((float4*)Xt)[tid + 1024] = ((const float4*)X)[tid + 1024];

    const float* W = attnW + HH;   // W2 = attnW[:, H:2H], row stride 2H
    const int hq = tid & 31, rr = tid >> 5;   // rr 0..31 -> rows 2rr, 2rr+1
    const int h0 = 4 * hq;

    float4 acc0 = make_float4(0.f, 0.f, 0.f, 0.f);
    float4 acc1 = acc0;

    #pragma unroll 1
    for (int kb = 0; kb < 4; ++kb) {
      __syncthreads();
      { // stage 128h x 32k quarter, transposed, padded stride 132
        int h = tid >> 3, koff = (tid & 7) * 4;
        float4 v = *(const float4*)(W + h * 256 + kb * 32 + koff);
        WT[(koff + 0) * 132 + h] = v.x;
        WT[(koff + 1) * 132 + h] = v.y;
        WT[(koff + 2) * 132 + h] = v.z;
        WT[(koff + 3) * 132 + h] = v.w;
      }
      __syncthreads();
      const float* xr0 = Xt + (2 * rr) * 128 + kb * 32;
      const float* xr1 = xr0 + 128;
      #pragma unroll
      for (int k4 = 0; k4 < 32; k4 += 4) {
        float4 xa = *(const float4*)(xr0 + k4);
        float4 xb = *(const float4*)(xr1 + k4);
        float4 w0 = *(const float4*)&WT[(k4 + 0) * 132 + h0];
        float4 w1 = *(const float4*)&WT[(k4 + 1) * 132 + h0];
        float4 w2 = *(const float4*)&WT[(k4 + 2) * 132 + h0];
        float4 w3 = *(const float4*)&WT[(k4 + 3) * 132 + h0];
        FMA4S(acc0, xa.x, w0); FMA4S(acc0, xa.y, w1);
        FMA4S(acc0, xa.z, w2); FMA4S(acc0, xa.w, w3);
        FMA4S(acc1, xb.x, w0); FMA4S(acc1, xb.y, w1);
        FMA4S(acc1, xb.z, w2); FMA4S(acc1, xb.w, w3);
      }
    }
    acc0.x = fexp2(TWO_LOG2E * acc0.x); acc0.y = fexp2(TWO_LOG2E * acc0.y);
    acc0.z = fexp2(TWO_LOG2E * acc0.z); acc0.w = fexp2(TWO_LOG2E * acc0.w);
    acc1.x = fexp2(TWO_LOG2E * acc1.x); acc1.y = fexp2(TWO_LOG2E * acc1.y);
    acc1.z = fexp2(TWO_LOG2E * acc1.z); acc1.w = fexp2(TWO_LOG2E * acc1.w);
    float* O = Pbuf + ((size_t)b * TT + r0) * HH;
    *(float4*)(O + (2 * rr) * 128 + h0)     = acc0;
    *(float4*)(O + (2 * rr + 1) * 128 + h0) = acc1;
  }
}

// ---------------------------------------------------------------------------
// K2: Ea[b,s,h] = exp2(2log2e * (decH[b,s,:]·W1[h,:] + attn_b[h])) -> Abuf.
// grid 512 = (8 row-tiles x 64 b), 256 threads, LDS-staged W^T.
// ---------------------------------------------------------------------------
__global__ __launch_bounds__(256, 2) void projA_kernel(
    const float* __restrict__ decH, const float* __restrict__ attnW,
    const float* __restrict__ attnb, float* __restrict__ Abuf)
{
  const int b  = blockIdx.x & 63;
  const int r0 = (blockIdx.x >> 6) * 16;
  const int tid = threadIdx.x;

  __shared__ __align__(16) float WT[64 * 128];  // 32 KB: W1^T for a k-half
  __shared__ __align__(16) float Xt[16 * 128];  // 8 KB

  const float* X = decH + ((size_t)b * TT + r0) * HH;
  const float* W = attnW;   // W1 = attnW[:, :H], row stride 2H

  ((float4*)Xt)[tid]       = ((const float4*)X)[tid];
  ((float4*)Xt)[256 + tid] = ((const float4*)X)[256 + tid];

  const int hq = tid & 31, rr = tid >> 5;
  const int h0 = 4 * hq;

  float4 acc0 = *(const float4*)(attnb + h0);
  float4 acc1 = acc0;

  for (int kb = 0; kb < 2; ++kb) {
    __syncthreads();  // protect WT overwrite
    {
      int h = tid >> 1, koff = (tid & 1) * 32;
      #pragma unroll
      for (int j = 0; j < 8; ++j) {
        float4 v = *(const float4*)(W + h * 256 + kb * 64 + koff + 4 * j);
        int kp = koff + 4 * j;
        WT[(kp + 0) * 128 + h] = v.x;
        WT[(kp + 1) * 128 + h] = v.y;
        WT[(kp + 2) * 128 + h] = v.z;
        WT[(kp + 3) * 128 + h] = v.w;
      }
    }
    __syncthreads();
    const float* xr0 = Xt + (2 * rr) * 128 + kb * 64;
    const float* xr1 = xr0 + 128;
    #pragma unroll
    for (int k4 = 0; k4 < 64; k4 += 4) {
      float4 xa = *(const float4*)(xr0 + k4);
      float4 xb = *(const float4*)(xr1 + k4);
      float4 w0 = *(const float4*)&WT[(k4 + 0) * 128 + h0];
      float4 w1 = *(const float4*)&WT[(k4 + 1) * 128 + h0];
      float4 w2 = *(const float4*)&WT[(k4 + 2) * 128 + h0];
      float4 w3 = *(const float4*)&WT[(k4 + 3) * 128 + h0];
      FMA4S(acc0, xa.x, w0); FMA4S(acc0, xa.y, w1);
      FMA4S(acc0, xa.z, w2); FMA4S(acc0, xa.w, w3);
      FMA4S(acc1, xb.x, w0); FMA4S(acc1, xb.y, w1);
      FMA4S(acc1, xb.z, w2); FMA4S(acc1, xb.w, w3);
    }
  }
  acc0.x = fexp2(TWO_LOG2E * acc0.x); acc0.y = fexp2(TWO_LOG2E * acc0.y);
  acc0.z = fexp2(TWO_LOG2E * acc0.z); acc0.w = fexp2(TWO_LOG2E * acc0.w);
  acc1.x = fexp2(TWO_LOG2E * acc1.x); acc1.y = fexp2(TWO_LOG2E * acc1.y);
  acc1.z = fexp2(TWO_LOG2E * acc1.z); acc1.w = fexp2(TWO_LOG2E * acc1.w);
  float* O = Abuf + ((size_t)b * TT + r0) * HH;
  *(float4*)(O + (2 * rr) * 128 + h0)     = acc0;
  *(float4*)(O + (2 * rr + 1) * 128 + h0) = acc1;
}

// ---------------------------------------------------------------------------
// K3 v5: attention + output with the y2 factorization:
//   ctx @ outW2^T = (w @ encH) @ outW2^T = w @ y2,  y2 = encH @ outW2^T [128x12]
// The old ctx loop (262K fma, ~0.5 MB LDS reads of staged encH per block) and
// the 64-deep out-stage become: y2 dots (~50K fma, broadcast-heavy LDS reads)
// + a 12-wide tail.  encH staging kept (reused by y2); a_lds ctx overlay gone.
// Energy stage unchanged (Ea/Ep precomputed, {fma,rcp,fma} inner loop).
// ---------------------------------------------------------------------------
#define AST 132  // padded row stride for a_lds / sc
#define Y2ST 20  // padded row stride for y2 (12 cols)

__global__ __launch_bounds__(512, 2) void attn_kernel(
    const float* __restrict__ encH, const float* __restrict__ decH,
    const float* __restrict__ Pbuf, const float* __restrict__ Abuf,
    const float* __restrict__ vw, const float* __restrict__ outW,
    const float* __restrict__ outb, float* __restrict__ out)
{
  const int b  = blockIdx.x >> 3;
  const int s0 = (blockIdx.x & 7) * 16;
  const int tid = threadIdx.x;

  __shared__ __align__(16) float buf[64 * 128];    // 32 KB: Ep^T-half (swizzled), later encH-half
  __shared__ __align__(16) float a_lds[16 * AST];  // Ea tile
  __shared__ __align__(16) float sc[16 * AST];     // scores -> weights
  __shared__ __align__(16) float dh[16 * 128];     // decH tile
  __shared__ __align__(16) float vl[HH];
  __shared__ __align__(16) float y2s[TT * Y2ST];   // 10 KB: y2 = encH @ outW2^T
  __shared__ __align__(16) float w2l[12 * AST];    // 6.3 KB: outW2 rows (padded)

  ((float4*)dh)[tid] = ((const float4*)(decH + ((size_t)b * TT + s0) * HH))[tid];
  if (tid < 32) ((float4*)vl)[tid] = ((const float4*)vw)[tid];
  {
    // Ea tile into padded a_lds (already exp'd by projA)
    int r = tid >> 5, c4 = (tid & 31) * 4;
    float4 av = *(const float4*)(Abuf + ((size_t)b * TT + s0 + r) * HH + c4);
    *(float4*)&a_lds[r * AST + c4] = av;
  }
  if (tid < 384) {  // outW2 = outW[:,128:256] -> w2l[f][k], stride AST (bank-spread)
    int f = tid >> 5, k = (tid & 31) * 4;
    float4 wv = *(const float4*)(outW + f * 256 + 128 + k);
    *(float4*)&w2l[f * AST + k] = wv;
  }

  const int u  = tid & 31;
  const int sl = tid >> 5;   // 0..15 decoder-step within tile
  const int uq = u & 15;     // t-quad within half
  const int uh = u >> 4;     // 0/1 h-half

  // ---- energies/scores ----
  for (int half = 0; half < 2; ++half) {
    const int tbase = half * 64;
    __syncthreads();  // prev buf use done; also covers initial staging
    #pragma unroll
    for (int i = 0; i < 4; ++i) {
      int flat = i * 2048 + tid * 4;
      int tp = flat >> 7;        // 0..63
      int h0 = flat & 127;
      float4 v = *(const float4*)(Pbuf + ((size_t)b * TT + tbase + tp) * HH + h0);
      int tq = tp >> 2, tr = tp & 3;
      buf[(h0 + 0) * 64 + 4 * ((tq ^ ((h0 + 0) >> 2)) & 15) + tr] = v.x;
      buf[(h0 + 1) * 64 + 4 * ((tq ^ ((h0 + 1) >> 2)) & 15) + tr] = v.y;
      buf[(h0 + 2) * 64 + 4 * ((tq ^ ((h0 + 2) >> 2)) & 15) + tr] = v.z;
      buf[(h0 + 3) * 64 + 4 * ((tq ^ ((h0 + 3) >> 2)) & 15) + tr] = v.w;
    }
    __syncthreads();
    float4 acc = make_float4(0.f, 0.f, 0.f, 0.f);
    const float* earow = a_lds + sl * AST;
    #pragma unroll 4
    for (int hh = 0; hh < 64; hh += 4) {
      const int h = uh * 64 + hh;
      float4 ea = *(const float4*)&earow[h];
      float4 va = *(const float4*)&vl[h];
      const int xoff = 4 * ((uq ^ ((h >> 2) & 15)) & 15);  // same for h..h+3
      float4 p0 = *(const float4*)&buf[(h + 0) * 64 + xoff];
      float4 p1 = *(const float4*)&buf[(h + 1) * 64 + xoff];
      float4 p2 = *(const float4*)&buf[(h + 2) * 64 + xoff];
      float4 p3 = *(const float4*)&buf[(h + 3) * 64 + xoff];
      acc.x = fmaf(va.x, frcp(fmaf(ea.x, p0.x, 1.f)), acc.x);
      acc.y = fmaf(va.x, frcp(fmaf(ea.x, p0.y, 1.f)), acc.y);
      acc.z = fmaf(va.x, frcp(fmaf(ea.x, p0.z, 1.f)), acc.z);
      acc.w = fmaf(va.x, frcp(fmaf(ea.x, p0.w, 1.f)), acc.w);
      acc.x = fmaf(va.y, frcp(fmaf(ea.y, p1.x, 1.f)), acc.x);
      acc.y = fmaf(va.y, frcp(fmaf(ea.y, p1.y, 1.f)), acc.y);
      acc.z = fmaf(va.y, frcp(fmaf(ea.y, p1.z, 1.f)), acc.z);
      acc.w = fmaf(va.y, frcp(fmaf(ea.y, p1.w, 1.f)), acc.w);
      acc.x = fmaf(va.z, frcp(fmaf(ea.z, p2.x, 1.f)), acc.x);
      acc.y = fmaf(va.z, frcp(fmaf(ea.z, p2.y, 1.f)), acc.y);
      acc.z = fmaf(va.z, frcp(fmaf(ea.z, p2.z, 1.f)), acc.z);
      acc.w = fmaf(va.z, frcp(fmaf(ea.z, p2.w, 1.f)), acc.w);
      acc.x = fmaf(va.w, frcp(fmaf(ea.w, p3.x, 1.f)), acc.x);
      acc.y = fmaf(va.w, frcp(fmaf(ea.w, p3.y, 1.f)), acc.y);
      acc.z = fmaf(va.w, frcp(fmaf(ea.w, p3.z, 1.f)), acc.z);
      acc.w = fmaf(va.w, frcp(fmaf(ea.w, p3.w, 1.f)), acc.w);
    }
    acc.x += __shfl_xor(acc.x, 16, 64);
    acc.y += __shfl_xor(acc.y, 16, 64);
    acc.z += __shfl_xor(acc.z, 16, 64);
    acc.w += __shfl_xor(acc.w, 16, 64);
    if (uh == 0) {
      float4 o;
      o.x = -2.f * acc.x; o.y = -2.f * acc.y;
      o.z = -2.f * acc.z; o.w = -2.f * acc.w;
      *(float4*)&sc[sl * AST + tbase + 4 * uq] = o;
    }
  }
  __syncthreads();

  // ---- softmax over t (per s row; 32 lanes x f4 = 128) ----
  {
    float4 sv = *(const float4*)&sc[sl * AST + 4 * u];
    float mx = fmaxf(fmaxf(sv.x, sv.y), fmaxf(sv.z, sv.w));
    #pragma unroll
    for (int msk = 1; msk <= 16; msk <<= 1) mx = fmaxf(mx, __shfl_xor(mx, msk, 64));
    float4 e;
    e.x = fexp2(LOG2E * (sv.x - mx));
    e.y = fexp2(LOG2E * (sv.y - mx));
    e.z = fexp2(LOG2E * (sv.z - mx));
    e.w = fexp2(LOG2E * (sv.w - mx));
    float sm = (e.x + e.y) + (e.z + e.w);
    #pragma unroll
    for (int msk = 1; msk <= 16; msk <<= 1) sm += __shfl_xor(sm, msk, 64);
    float r = frcp(sm);
    e.x *= r; e.y *= r; e.z *= r; e.w *= r;
    *(float4*)&sc[sl * AST + 4 * u] = e;
  }

  // ---- y2 = encH @ outW2^T, per half (768 outputs: t_local x 12 f) ----
  for (int half = 0; half < 2; ++half) {
    const int tbase = half * 64;
    __syncthreads();  // buf free (energy reads / prev y2 reads done)
    #pragma unroll
    for (int i = 0; i < 4; ++i) {
      int flat = i * 2048 + tid * 4;
      int tp = flat >> 7;
      int hh0 = flat & 127;
      *(float4*)&buf[tp * 128 + hh0] =
          *(const float4*)(encH + ((size_t)b * TT + tbase + tp) * HH + hh0);
    }
    __syncthreads();
    {
      int j = tid;                      // j in [0,768): t = j/12, f = j%12
      int t = j / 12, f = j - 12 * t;
      float a = 0.f;
      const float* br = buf + t * 128;
      const float* wr = w2l + f * AST;
      #pragma unroll 8
      for (int k = 0; k < 32; ++k) {
        float4 bv = *(const float4*)(br + 4 * k);
        float4 wv = *(const float4*)(wr + 4 * k);
        ACC4(bv, wv, a);
      }
      y2s[(tbase + t) * Y2ST + f] = a;
      if (tid < 256) {
        int j2 = tid + 512;
        int t2 = j2 / 12, f2 = j2 - 12 * t2;
        float a2 = 0.f;
        const float* br2 = buf + t2 * 128;
        const float* wr2 = w2l + f2 * AST;
        #pragma unroll 8
        for (int k = 0; k < 32; ++k) {
          float4 bv = *(const float4*)(br2 + 4 * k);
          float4 wv = *(const float4*)(wr2 + 4 * k);
          ACC4(bv, wv, a2);
        }
        y2s[(tbase + t2) * Y2ST + f2] = a2;
      }
    }
  }
  __syncthreads();  // y2 complete; softmax weights in sc

  // ---- out[b,s,f] = outb[f] + dh[s,:]·outW1[f,:] + sc[s,:]·y2[:,f] ----
  if (tid < 192) {
    int s = tid / 12, f = tid - 12 * (tid / 12);
    float acc = outb[f];
    const float4* w4 = (const float4*)(outW + f * 256);  // outW1 row (global/L1)
    const float4* d4 = (const float4*)(dh + s * 128);
    #pragma unroll
    for (int k = 0; k < 32; ++k) {
      float4 wv = w4[k], dv = d4[k];
      acc = fmaf(wv.x, dv.x, acc); acc = fmaf(wv.y, dv.y, acc);
      acc = fmaf(wv.z, dv.z, acc); acc = fmaf(wv.w, dv.w, acc);
    }
    const float* wrow = sc + s * AST;
    #pragma unroll 8
    for (int t = 0; t < TT; ++t)
      acc = fmaf(wrow[t], y2s[t * Y2ST + f], acc);
    out[((size_t)b * TT + s0 + s) * FIN + f] = acc;
  }
}

// ---------------------------------------------------------------------------
extern "C" void kernel_launch(void* const* d_in, const int* in_sizes, int n_in,
                              void* d_out, int out_size, void* d_ws, size_t ws_size,
                              hipStream_t stream)
{
  const float* x     = (const float*)d_in[0];
  const float* eWih  = (const float*)d_in[1];
  const float* eWhh  = (const float*)d_in[2];
  const float* eb    = (const float*)d_in[3];
  const float* dWih  = (const float*)d_in[4];
  const float* dWhh  = (const float*)d_in[5];
  const float* db    = (const float*)d_in[6];
  const float* attnW = (const float*)d_in[7];
  const float* attnb = (const float*)d_in[8];
  const float* vw    = (const float*)d_in[9];
  const float* outW  = (const float*)d_in[10];
  const float* outb  = (const float*)d_in[11];
  float* out = (float*)d_out;

  float* ws   = (float*)d_ws;
  const size_t SEG = (size_t)BB * TT * HH;  // 1,048,576 floats = 4 MB
  float* encH = ws;
  float* decH = ws + SEG;
  float* Pbuf = ws + 2 * SEG;   // Ep = exp2(2log2e * P)
  float* Abuf = ws + 3 * SEG;   // Ea = exp2(2log2e * A)

  lstm_enc_kernel<<<64, 1024, 0, stream>>>(x, eWih, eWhh, eb, encH, decH);
  lstm_dec_p_kernel<<<192, 1024, 0, stream>>>(x, dWih, dWhh, db, attnW, encH, decH, Pbuf);
  projA_kernel<<<512, 256, 0, stream>>>(decH, attnW, attnb, Abuf);
  attn_kernel<<<512, 512, 0, stream>>>(encH, decH, Pbuf, Abuf, vw, outW, outb, out);
}

// Round 8
// 314.733 us; speedup vs baseline: 1.1590x; 1.0372x over previous
//
#include <hip/hip_runtime.h>
#include <hip/hip_bf16.h>

// Problem dims
#define BB 64
#define TT 128
#define FIN 12
#define HH 128

#define LOG2E 1.4426950408889634f
#define TWO_LOG2E 2.8853900817779268f

__device__ __forceinline__ float fexp2(float x) { return __builtin_amdgcn_exp2f(x); }
__device__ __forceinline__ float frcp(float x)  { return __builtin_amdgcn_rcpf(x); }

// tanh(x) = 1 - 2/(1+e^{2x}); correct limits at +/-inf via exp2->{inf,0}
__device__ __forceinline__ float tanh_f(float x) {
  return 1.0f - 2.0f * frcp(1.0f + fexp2(TWO_LOG2E * x));
}
__device__ __forceinline__ float sigm_f(float x) {
  return frcp(1.0f + fexp2(-LOG2E * x));
}

// DPP 8-lane sum (over lane bits 0..2). Pure VALU -- no DS traffic.
template <int CTRL>
__device__ __forceinline__ float dpp_addstage(float v) {
  int s = __builtin_amdgcn_update_dpp(0, __float_as_int(v), CTRL, 0xF, 0xF, true);
  return v + __int_as_float(s);
}
__device__ __forceinline__ float red8(float v) {
  v = dpp_addstage<0xB1>(v);   // quad_perm [1,0,3,2]: partner lane^1
  v = dpp_addstage<0x4E>(v);   // quad_perm [2,3,0,1]: partner lane^2
  v = dpp_addstage<0x141>(v);  // row_half_mirror: partner lane^7 -> 8-lane total
  return v;
}

#define FMA4S(acc, s, v) do { \
  acc.x = fmaf((s), (v).x, acc.x); \
  acc.y = fmaf((s), (v).y, acc.y); \
  acc.z = fmaf((s), (v).z, acc.z); \
  acc.w = fmaf((s), (v).w, acc.w); } while (0)

#define ACC4(hv, wv, a) do { \
  a = fmaf((hv).x, (wv).x, a); a = fmaf((hv).y, (wv).y, a); \
  a = fmaf((hv).z, (wv).z, a); a = fmaf((hv).w, (wv).w, a); } while (0)

// ---------------------------------------------------------------------------
// Shared LSTM phase body -- v6 SCALAR structure (measured 107.6/108.2 us).
// PKFMA (round 6) regressed to 125us: inline-asm chains blocked scheduling.
// ---------------------------------------------------------------------------
__device__ __forceinline__ void lstm_phase(
    const float* __restrict__ Wih, const float* __restrict__ Whh,
    const float* __restrict__ bias, float* __restrict__ Hout /* b-offset applied */,
    float* __restrict__ xs, float (*hbuf)[160], float* __restrict__ hist,
    const int tid, const int q, const int i, float& c)
{
  const int xo   = (q < 4) ? 3 * q : 0;
  const float xz = (q < 4) ? 1.0f : 0.0f;

  float4 wg[4][4];
  #pragma unroll
  for (int g = 0; g < 4; ++g)
    #pragma unroll
    for (int j = 0; j < 4; ++j)
      wg[g][j] = *(const float4*)(Whh + ((g * HH + i) * HH) + 16 * q + 4 * j);

  float wx[4][3];
  #pragma unroll
  for (int g = 0; g < 4; ++g)
    #pragma unroll
    for (int j = 0; j < 3; ++j)
      wx[g][j] = Wih[(g * HH + i) * FIN + xo + j] * xz;

  const float bi = bias[i], bf = bias[HH + i], bg = bias[2 * HH + i], bo = bias[3 * HH + i];

  int ts = 0;
  #pragma unroll 1
  for (int half = 0; half < 2; ++half) {
    #pragma unroll 1
    for (int tt = 0; tt < 64; ++tt, ++ts) {
      const int t = half * 64 + tt;
      __syncthreads();  // h(t) ready in hbuf[ts&1]; hist copy reads done
      const float* hb = (const float*)hbuf[ts & 1] + q * 20;
      float4 h0 = *(const float4*)(hb + 0);
      float4 h1 = *(const float4*)(hb + 4);
      float4 h2 = *(const float4*)(hb + 8);
      float4 h3 = *(const float4*)(hb + 12);

      const float* xt = xs + t * FIN + xo;
      float x0 = xt[0], x1 = xt[1], x2 = xt[2];
      float ai = wx[0][0] * x0 + wx[0][1] * x1 + wx[0][2] * x2;
      float af = wx[1][0] * x0 + wx[1][1] * x1 + wx[1][2] * x2;
      float ag = wx[2][0] * x0 + wx[2][1] * x1 + wx[2][2] * x2;
      float ao = wx[3][0] * x0 + wx[3][1] * x1 + wx[3][2] * x2;

      ACC4(h0, wg[0][0], ai); ACC4(h0, wg[1][0], af); ACC4(h0, wg[2][0], ag); ACC4(h0, wg[3][0], ao);
      ACC4(h1, wg[0][1], ai); ACC4(h1, wg[1][1], af); ACC4(h1, wg[2][1], ag); ACC4(h1, wg[3][1], ao);
      ACC4(h2, wg[0][2], ai); ACC4(h2, wg[1][2], af); ACC4(h2, wg[2][2], ag); ACC4(h2, wg[3][2], ao);
      ACC4(h3, wg[0][3], ai); ACC4(h3, wg[1][3], af); ACC4(h3, wg[2][3], ag); ACC4(h3, wg[3][3], ao);

      ai = red8(ai); af = red8(af); ag = red8(ag); ao = red8(ao);

      if (q == 0) {
        float zi = sigm_f(ai + bi);
        float zf = sigm_f(af + bf);
        float zg = tanh_f(ag + bg);
        float zo = sigm_f(ao + bo);
        c = fmaf(zf, c, zi * zg);
        float hn = zo * tanh_f(c);
        hbuf[(ts + 1) & 1][(i >> 4) * 20 + (i & 15)] = hn;
        hist[tt * HH + i] = hn;   // LDS only -- no vm op in the step loop
      }
    }
    __syncthreads();  // hist writes visible
    {
      float4* dst = (float4*)(Hout + (size_t)(half * 64) * HH);
      const float4* src = (const float4*)hist;
      dst[tid]        = src[tid];
      dst[tid + 1024] = src[tid + 1024];
    }
  }
}

// ---------------------------------------------------------------------------
// K1a: encoder LSTM (64 blocks) -> encH.  cT stashed in decH row 0 (read by
// decoder before first overwrite); hT is encH row 127.
// ---------------------------------------------------------------------------
__global__ __launch_bounds__(1024, 4) void lstm_enc_kernel(
    const float* __restrict__ x,
    const float* __restrict__ eWih, const float* __restrict__ eWhh, const float* __restrict__ eb,
    float* __restrict__ encH, float* __restrict__ decH)
{
  const int b   = blockIdx.x;
  const int tid = threadIdx.x;
  const int q   = tid & 7;
  const int i   = tid >> 3;

  __shared__ __align__(16) float xs[TT * FIN];
  __shared__ __align__(16) float hbuf[2][160];
  __shared__ __align__(16) float hist[64 * HH];

  if (tid < (TT * FIN / 4))
    ((float4*)xs)[tid] = ((const float4*)(x + (size_t)b * TT * FIN))[tid];
  if (tid < 320) ((float*)hbuf)[tid] = 0.0f;
  float c = 0.0f;

  lstm_phase(eWih, eWhh, eb, encH + (size_t)b * TT * HH, xs, hbuf, hist, tid, q, i, c);

  if (q == 0) decH[(size_t)b * TT * HH + i] = c;   // cT handoff (row 0, pre-overwrite)
}

// ---------------------------------------------------------------------------
// K1b: heterogeneous grid (256 blocks x 1024 thr when y2buf present).
//  blocks 0..63:   decoder LSTM (h0 = encH row 127, c0 = decH row 0) -> decH.
//  blocks 64..191: Ep = exp2(2log2e * encH@W2^T) -> Pbuf.
//  blocks 192..255: y2[b,t,f] = encH[b,t,:]·outW2[f,:] -> y2buf (stride 16).
// P and y2 depend only on encH -> both fully hidden under the decoder.
// ---------------------------------------------------------------------------
__global__ __launch_bounds__(1024, 4) void lstm_dec_p_kernel(
    const float* __restrict__ x,
    const float* __restrict__ dWih, const float* __restrict__ dWhh, const float* __restrict__ db,
    const float* __restrict__ attnW, const float* __restrict__ outW,
    const float* __restrict__ encH,
    float* __restrict__ decH, float* __restrict__ Pbuf, float* __restrict__ y2buf)
{
  __shared__ __align__(16) float smem[12416];   // 48.5 KB, overlaid per path
  const int tid = threadIdx.x;

  if (blockIdx.x < 64) {
    // ---- decoder LSTM ----
    const int b = blockIdx.x;
    const int q = tid & 7;
    const int i = tid >> 3;
    float* xs           = smem;                          // 1536 floats
    float (*hbuf)[160]  = (float(*)[160])(smem + 1536);  // 320 floats
    float* hist         = smem + 1856;                   // 8192 floats

    if (tid < (TT * FIN / 4))
      ((float4*)xs)[tid] = ((const float4*)(x + (size_t)b * TT * FIN))[tid];
    if (tid < 128) {  // h0 = hT = encH row 127, skewed into hbuf[0]
      float hv = encH[((size_t)b * TT + 127) * HH + tid];
      hbuf[0][(tid >> 4) * 20 + (tid & 15)] = hv;
    }
    float c = 0.0f;
    if (q == 0) c = decH[(size_t)b * TT * HH + i];   // c0 = cT (stashed by enc)

    lstm_phase(dWih, dWhh, db, decH + (size_t)b * TT * HH, xs, hbuf, hist, tid, q, i, c);
  } else if (blockIdx.x < 192) {
    // ---- P projection (64-row tile) ----
    const int pb = blockIdx.x - 64;
    const int b  = pb & 63;
    const int r0 = (pb >> 6) * 64;
    float* WT = smem;          // [32][132] padded k-major W2^T quarter, 4224 floats
    float* Xt = smem + 4224;   // [64][128] encH tile, 8192 floats

    const float* X = encH + ((size_t)b * TT + r0) * HH;
    ((float4*)Xt)[tid]        = ((const float4*)X)[tid];
    ((float4*)Xt)[tid + 1024] = ((const float4*)X)[tid + 1024];

    const float* W = attnW + HH;   // W2 = attnW[:, H:2H], row stride 2H
    const int hq = tid & 31, rr = tid >> 5;   // rr 0..31 -> rows 2rr, 2rr+1
    const int h0 = 4 * hq;

    float4 acc0 = make_float4(0.f, 0.f, 0.f, 0.f);
    float4 acc1 = acc0;

    #pragma unroll 1
    for (int kb = 0; kb < 4; ++kb) {
      __syncthreads();
      { // stage 128h x 32k quarter, transposed, padded stride 132
        int h = tid >> 3, koff = (tid & 7) * 4;
        float4 v = *(const float4*)(W + h * 256 + kb * 32 + koff);
        WT[(koff + 0) * 132 + h] = v.x;
        WT[(koff + 1) * 132 + h] = v.y;
        WT[(koff + 2) * 132 + h] = v.z;
        WT[(koff + 3) * 132 + h] = v.w;
      }
      __syncthreads();
      const float* xr0 = Xt + (2 * rr) * 128 + kb * 32;
      const float* xr1 = xr0 + 128;
      #pragma unroll
      for (int k4 = 0; k4 < 32; k4 += 4) {
        float4 xa = *(const float4*)(xr0 + k4);
        float4 xb = *(const float4*)(xr1 + k4);
        float4 w0 = *(const float4*)&WT[(k4 + 0) * 132 + h0];
        float4 w1 = *(const float4*)&WT[(k4 + 1) * 132 + h0];
        float4 w2 = *(const float4*)&WT[(k4 + 2) * 132 + h0];
        float4 w3 = *(const float4*)&WT[(k4 + 3) * 132 + h0];
        FMA4S(acc0, xa.x, w0); FMA4S(acc0, xa.y, w1);
        FMA4S(acc0, xa.z, w2); FMA4S(acc0, xa.w, w3);
        FMA4S(acc1, xb.x, w0); FMA4S(acc1, xb.y, w1);
        FMA4S(acc1, xb.z, w2); FMA4S(acc1, xb.w, w3);
      }
    }
    acc0.x = fexp2(TWO_LOG2E * acc0.x); acc0.y = fexp2(TWO_LOG2E * acc0.y);
    acc0.z = fexp2(TWO_LOG2E * acc0.z); acc0.w = fexp2(TWO_LOG2E * acc0.w);
    acc1.x = fexp2(TWO_LOG2E * acc1.x); acc1.y = fexp2(TWO_LOG2E * acc1.y);
    acc1.z = fexp2(TWO_LOG2E * acc1.z); acc1.w = fexp2(TWO_LOG2E * acc1.w);
    float* O = Pbuf + ((size_t)b * TT + r0) * HH;
    *(float4*)(O + (2 * rr) * 128 + h0)     = acc0;
    *(float4*)(O + (2 * rr + 1) * 128 + h0) = acc1;
  } else if (y2buf) {
    // ---- y2 = encH @ outW2^T, one block per b (hidden under decoder) ----
    const int b = blockIdx.x - 192;
    float* w2l = smem;   // [12][132] outW2 rows, padded
    if (tid < 384) {
      int f = tid >> 5, k = (tid & 31) * 4;
      float4 wv = *(const float4*)(outW + f * 256 + 128 + k);
      *(float4*)&w2l[f * 132 + k] = wv;
    }
    __syncthreads();
    for (int j = tid; j < TT * 12; j += 1024) {
      int t = j / 12, f = j - 12 * t;
      const float* er = encH + ((size_t)b * TT + t) * HH;   // 12 lanes share a row (L1)
      const float* wr = w2l + f * 132;
      float a = 0.f;
      #pragma unroll 8
      for (int k = 0; k < 32; ++k) {
        float4 ev = *(const float4*)(er + 4 * k);
        float4 wv = *(const float4*)(wr + 4 * k);
        ACC4(ev, wv, a);
      }
      y2buf[b * (TT * 16) + t * 16 + f] = a;
    }
  }
}

// ---------------------------------------------------------------------------
// K2: Ea[b,s,h] = exp2(2log2e * (decH[b,s,:]·W1[h,:] + attn_b[h])) -> Abuf.
// grid 512 = (8 row-tiles x 64 b), 256 threads, LDS-staged W^T.
// ---------------------------------------------------------------------------
__global__ __launch_bounds__(256, 2) void projA_kernel(
    const float* __restrict__ decH, const float* __restrict__ attnW,
    const float* __restrict__ attnb, float* __restrict__ Abuf)
{
  const int b  = blockIdx.x & 63;
  const int r0 = (blockIdx.x >> 6) * 16;
  const int tid = threadIdx.x;

  __shared__ __align__(16) float WT[64 * 128];  // 32 KB: W1^T for a k-half
  __shared__ __align__(16) float Xt[16 * 128];  // 8 KB

  const float* X = decH + ((size_t)b * TT + r0) * HH;
  const float* W = attnW;   // W1 = attnW[:, :H], row stride 2H

  ((float4*)Xt)[tid]       = ((const float4*)X)[tid];
  ((float4*)Xt)[256 + tid] = ((const float4*)X)[256 + tid];

  const int hq = tid & 31, rr = tid >> 5;
  const int h0 = 4 * hq;

  float4 acc0 = *(const float4*)(attnb + h0);
  float4 acc1 = acc0;

  for (int kb = 0; kb < 2; ++kb) {
    __syncthreads();  // protect WT overwrite
    {
      int h = tid >> 1, koff = (tid & 1) * 32;
      #pragma unroll
      for (int j = 0; j < 8; ++j) {
        float4 v = *(const float4*)(W + h * 256 + kb * 64 + koff + 4 * j);
        int kp = koff + 4 * j;
        WT[(kp + 0) * 128 + h] = v.x;
        WT[(kp + 1) * 128 + h] = v.y;
        WT[(kp + 2) * 128 + h] = v.z;
        WT[(kp + 3) * 128 + h] = v.w;
      }
    }
    __syncthreads();
    const float* xr0 = Xt + (2 * rr) * 128 + kb * 64;
    const float* xr1 = xr0 + 128;
    #pragma unroll
    for (int k4 = 0; k4 < 64; k4 += 4) {
      float4 xa = *(const float4*)(xr0 + k4);
      float4 xb = *(const float4*)(xr1 + k4);
      float4 w0 = *(const float4*)&WT[(k4 + 0) * 128 + h0];
      float4 w1 = *(const float4*)&WT[(k4 + 1) * 128 + h0];
      float4 w2 = *(const float4*)&WT[(k4 + 2) * 128 + h0];
      float4 w3 = *(const float4*)&WT[(k4 + 3) * 128 + h0];
      FMA4S(acc0, xa.x, w0); FMA4S(acc0, xa.y, w1);
      FMA4S(acc0, xa.z, w2); FMA4S(acc0, xa.w, w3);
      FMA4S(acc1, xb.x, w0); FMA4S(acc1, xb.y, w1);
      FMA4S(acc1, xb.z, w2); FMA4S(acc1, xb.w, w3);
    }
  }
  acc0.x = fexp2(TWO_LOG2E * acc0.x); acc0.y = fexp2(TWO_LOG2E * acc0.y);
  acc0.z = fexp2(TWO_LOG2E * acc0.z); acc0.w = fexp2(TWO_LOG2E * acc0.w);
  acc1.x = fexp2(TWO_LOG2E * acc1.x); acc1.y = fexp2(TWO_LOG2E * acc1.y);
  acc1.z = fexp2(TWO_LOG2E * acc1.z); acc1.w = fexp2(TWO_LOG2E * acc1.w);
  float* O = Abuf + ((size_t)b * TT + r0) * HH;
  *(float4*)(O + (2 * rr) * 128 + h0)     = acc0;
  *(float4*)(O + (2 * rr + 1) * 128 + h0) = acc1;
}

// ---------------------------------------------------------------------------
// K3 v6: attention + output.  HY2=true: y2 precomputed under the decoder ->
// this kernel drops both encH-staging halves, the y2 dot loops, and w2l:
// stage Ea/dh/y2 -> Ep energies -> softmax -> 12-wide tail.
// HY2=false: round-7 behavior verbatim (workspace-size fallback).
// ---------------------------------------------------------------------------
#define AST 132  // padded row stride for a_lds / sc
#define Y2ST 20  // padded row stride for y2 (12 cols used)

template <bool HY2>
__global__ __launch_bounds__(512, 2) void attn_kernel(
    const float* __restrict__ encH, const float* __restrict__ decH,
    const float* __restrict__ Pbuf, const float* __restrict__ Abuf,
    const float* __restrict__ y2buf,
    const float* __restrict__ vw, const float* __restrict__ outW,
    const float* __restrict__ outb, float* __restrict__ out)
{
  const int b  = blockIdx.x >> 3;
  const int s0 = (blockIdx.x & 7) * 16;
  const int tid = threadIdx.x;

  __shared__ __align__(16) float buf[64 * 128];    // 32 KB: Ep^T-half (swizzled)
  __shared__ __align__(16) float a_lds[16 * AST];  // Ea tile
  __shared__ __align__(16) float sc[16 * AST];     // scores -> weights
  __shared__ __align__(16) float dh[16 * 128];     // decH tile
  __shared__ __align__(16) float vl[HH];
  __shared__ __align__(16) float y2s[TT * Y2ST];   // 10 KB: y2 = encH @ outW2^T
  __shared__ __align__(16) float w2l[12 * AST];    // used only when !HY2

  ((float4*)dh)[tid] = ((const float4*)(decH + ((size_t)b * TT + s0) * HH))[tid];
  if (tid < 32) ((float4*)vl)[tid] = ((const float4*)vw)[tid];
  {
    // Ea tile into padded a_lds (already exp'd by projA)
    int r = tid >> 5, c4 = (tid & 31) * 4;
    float4 av = *(const float4*)(Abuf + ((size_t)b * TT + s0 + r) * HH + c4);
    *(float4*)&a_lds[r * AST + c4] = av;
  }
  if constexpr (HY2) {
    if (tid < 512) {  // 512 f4 = full [128][16] y2 slab; cols 12-15 unused
      float4 v = ((const float4*)(y2buf + (size_t)b * (TT * 16)))[tid];
      int t = tid >> 2, g = (tid & 3) * 4;
      *(float4*)&y2s[t * Y2ST + g] = v;
    }
  } else {
    if (tid < 384) {  // outW2 rows -> w2l (padded stride, bank-spread)
      int f = tid >> 5, k = (tid & 31) * 4;
      float4 wv = *(const float4*)(outW + f * 256 + 128 + k);
      *(float4*)&w2l[f * AST + k] = wv;
    }
  }

  const int u  = tid & 31;
  const int sl = tid >> 5;   // 0..15 decoder-step within tile
  const int uq = u & 15;     // t-quad within half
  const int uh = u >> 4;     // 0/1 h-half

  // ---- energies/scores ----
  for (int half = 0; half < 2; ++half) {
    const int tbase = half * 64;
    __syncthreads();  // prev buf use done; also covers initial staging
    #pragma unroll
    for (int i = 0; i < 4; ++i) {
      int flat = i * 2048 + tid * 4;
      int tp = flat >> 7;        // 0..63
      int h0 = flat & 127;
      float4 v = *(const float4*)(Pbuf + ((size_t)b * TT + tbase + tp) * HH + h0);
      int tq = tp >> 2, tr = tp & 3;
      buf[(h0 + 0) * 64 + 4 * ((tq ^ ((h0 + 0) >> 2)) & 15) + tr] = v.x;
      buf[(h0 + 1) * 64 + 4 * ((tq ^ ((h0 + 1) >> 2)) & 15) + tr] = v.y;
      buf[(h0 + 2) * 64 + 4 * ((tq ^ ((h0 + 2) >> 2)) & 15) + tr] = v.z;
      buf[(h0 + 3) * 64 + 4 * ((tq ^ ((h0 + 3) >> 2)) & 15) + tr] = v.w;
    }
    __syncthreads();
    float4 acc = make_float4(0.f, 0.f, 0.f, 0.f);
    const float* earow = a_lds + sl * AST;
    #pragma unroll 4
    for (int hh = 0; hh < 64; hh += 4) {
      const int h = uh * 64 + hh;
      float4 ea = *(const float4*)&earow[h];
      float4 va = *(const float4*)&vl[h];
      const int xoff = 4 * ((uq ^ ((h >> 2) & 15)) & 15);  // same for h..h+3
      float4 p0 = *(const float4*)&buf[(h + 0) * 64 + xoff];
      float4 p1 = *(const float4*)&buf[(h + 1) * 64 + xoff];
      float4 p2 = *(const float4*)&buf[(h + 2) * 64 + xoff];
      float4 p3 = *(const float4*)&buf[(h + 3) * 64 + xoff];
      acc.x = fmaf(va.x, frcp(fmaf(ea.x, p0.x, 1.f)), acc.x);
      acc.y = fmaf(va.x, frcp(fmaf(ea.x, p0.y, 1.f)), acc.y);
      acc.z = fmaf(va.x, frcp(fmaf(ea.x, p0.z, 1.f)), acc.z);
      acc.w = fmaf(va.x, frcp(fmaf(ea.x, p0.w, 1.f)), acc.w);
      acc.x = fmaf(va.y, frcp(fmaf(ea.y, p1.x, 1.f)), acc.x);
      acc.y = fmaf(va.y, frcp(fmaf(ea.y, p1.y, 1.f)), acc.y);
      acc.z = fmaf(va.y, frcp(fmaf(ea.y, p1.z, 1.f)), acc.z);
      acc.w = fmaf(va.y, frcp(fmaf(ea.y, p1.w, 1.f)), acc.w);
      acc.x = fmaf(va.z, frcp(fmaf(ea.z, p2.x, 1.f)), acc.x);
      acc.y = fmaf(va.z, frcp(fmaf(ea.z, p2.y, 1.f)), acc.y);
      acc.z = fmaf(va.z, frcp(fmaf(ea.z, p2.z, 1.f)), acc.z);
      acc.w = fmaf(va.z, frcp(fmaf(ea.z, p2.w, 1.f)), acc.w);
      acc.x = fmaf(va.w, frcp(fmaf(ea.w, p3.x, 1.f)), acc.x);
      acc.y = fmaf(va.w, frcp(fmaf(ea.w, p3.y, 1.f)), acc.y);
      acc.z = fmaf(va.w, frcp(fmaf(ea.w, p3.z, 1.f)), acc.z);
      acc.w = fmaf(va.w, frcp(fmaf(ea.w, p3.w, 1.f)), acc.w);
    }
    acc.x += __shfl_xor(acc.x, 16, 64);
    acc.y += __shfl_xor(acc.y, 16, 64);
    acc.z += __shfl_xor(acc.z, 16, 64);
    acc.w += __shfl_xor(acc.w, 16, 64);
    if (uh == 0) {
      float4 o;
      o.x = -2.f * acc.x; o.y = -2.f * acc.y;
      o.z = -2.f * acc.z; o.w = -2.f * acc.w;
      *(float4*)&sc[sl * AST + tbase + 4 * uq] = o;
    }
  }
  __syncthreads();

  // ---- softmax over t (per s row; 32 lanes x f4 = 128) ----
  {
    float4 sv = *(const float4*)&sc[sl * AST + 4 * u];
    float mx = fmaxf(fmaxf(sv.x, sv.y), fmaxf(sv.z, sv.w));
    #pragma unroll
    for (int msk = 1; msk <= 16; msk <<= 1) mx = fmaxf(mx, __shfl_xor(mx, msk, 64));
    float4 e;
    e.x = fexp2(LOG2E * (sv.x - mx));
    e.y = fexp2(LOG2E * (sv.y - mx));
    e.z = fexp2(LOG2E * (sv.z - mx));
    e.w = fexp2(LOG2E * (sv.w - mx));
    float sm = (e.x + e.y) + (e.z + e.w);
    #pragma unroll
    for (int msk = 1; msk <= 16; msk <<= 1) sm += __shfl_xor(sm, msk, 64);
    float r = frcp(sm);
    e.x *= r; e.y *= r; e.z *= r; e.w *= r;
    *(float4*)&sc[sl * AST + 4 * u] = e;
  }

  if constexpr (!HY2) {
    // ---- y2 = encH @ outW2^T, per half (768 outputs: t_local x 12 f) ----
    for (int half = 0; half < 2; ++half) {
      const int tbase = half * 64;
      __syncthreads();  // buf free (energy reads / prev y2 reads done)
      #pragma unroll
      for (int i = 0; i < 4; ++i) {
        int flat = i * 2048 + tid * 4;
        int tp = flat >> 7;
        int hh0 = flat & 127;
        *(float4*)&buf[tp * 128 + hh0] =
            *(const float4*)(encH + ((size_t)b * TT + tbase + tp) * HH + hh0);
      }
      __syncthreads();
      {
        int j = tid;                      // j in [0,768): t = j/12, f = j%12
        int t = j / 12, f = j - 12 * t;
        float a = 0.f;
        const float* br = buf + t * 128;
        const float* wr = w2l + f * AST;
        #pragma unroll 8
        for (int k = 0; k < 32; ++k) {
          float4 bv = *(const float4*)(br + 4 * k);
          float4 wv = *(const float4*)(wr + 4 * k);
          ACC4(bv, wv, a);
        }
        y2s[(tbase + t) * Y2ST + f] = a;
        if (tid < 256) {
          int j2 = tid + 512;
          int t2 = j2 / 12, f2 = j2 - 12 * t2;
          float a2 = 0.f;
          const float* br2 = buf + t2 * 128;
          const float* wr2 = w2l + f2 * AST;
          #pragma unroll 8
          for (int k = 0; k < 32; ++k) {
            float4 bv = *(const float4*)(br2 + 4 * k);
            float4 wv = *(const float4*)(wr2 + 4 * k);
            ACC4(bv, wv, a2);
          }
          y2s[(tbase + t2) * Y2ST + f2] = a2;
        }
      }
    }
  }
  __syncthreads();  // y2 staged/complete; softmax weights final in sc

  // ---- out[b,s,f] = outb[f] + dh[s,:]·outW1[f,:] + sc[s,:]·y2[:,f] ----
  if (tid < 192) {
    int s = tid / 12, f = tid - 12 * (tid / 12);
    float acc = outb[f];
    const float4* w4 = (const float4*)(outW + f * 256);  // outW1 row (global/L1)
    const float4* d4 = (const float4*)(dh + s * 128);
    #pragma unroll
    for (int k = 0; k < 32; ++k) {
      float4 wv = w4[k], dv = d4[k];
      acc = fmaf(wv.x, dv.x, acc); acc = fmaf(wv.y, dv.y, acc);
      acc = fmaf(wv.z, dv.z, acc); acc = fmaf(wv.w, dv.w, acc);
    }
    const float* wrow = sc + s * AST;
    #pragma unroll 8
    for (int t = 0; t < TT; ++t)
      acc = fmaf(wrow[t], y2s[t * Y2ST + f], acc);
    out[((size_t)b * TT + s0 + s) * FIN + f] = acc;
  }
}

// ---------------------------------------------------------------------------
extern "C" void kernel_launch(void* const* d_in, const int* in_sizes, int n_in,
                              void* d_out, int out_size, void* d_ws, size_t ws_size,
                              hipStream_t stream)
{
  const float* x     = (const float*)d_in[0];
  const float* eWih  = (const float*)d_in[1];
  const float* eWhh  = (const float*)d_in[2];
  const float* eb    = (const float*)d_in[3];
  const float* dWih  = (const float*)d_in[4];
  const float* dWhh  = (const float*)d_in[5];
  const float* db    = (const float*)d_in[6];
  const float* attnW = (const float*)d_in[7];
  const float* attnb = (const float*)d_in[8];
  const float* vw    = (const float*)d_in[9];
  const float* outW  = (const float*)d_in[10];
  const float* outb  = (const float*)d_in[11];
  float* out = (float*)d_out;

  float* ws   = (float*)d_ws;
  const size_t SEG = (size_t)BB * TT * HH;  // 1,048,576 floats = 4 MB
  float* encH = ws;
  float* decH = ws + SEG;
  float* Pbuf = ws + 2 * SEG;   // Ep = exp2(2log2e * P)
  float* Abuf = ws + 3 * SEG;   // Ea = exp2(2log2e * A)
  float* y2buf = ws + 4 * SEG;  // [BB][TT][16] y2, if workspace allows

  const size_t need_bytes = (4 * SEG + (size_t)BB * TT * 16) * sizeof(float);
  const bool have_y2 = ws_size >= need_bytes;

  lstm_enc_kernel<<<64, 1024, 0, stream>>>(x, eWih, eWhh, eb, encH, decH);
  if (have_y2) {
    lstm_dec_p_kernel<<<256, 1024, 0, stream>>>(x, dWih, dWhh, db, attnW, outW,
                                                encH, decH, Pbuf, y2buf);
    projA_kernel<<<512, 256, 0, stream>>>(decH, attnW, attnb, Abuf);
    attn_kernel<true><<<512, 512, 0, stream>>>(encH, decH, Pbuf, Abuf, y2buf,
                                               vw, outW, outb, out);
  } else {
    lstm_dec_p_kernel<<<192, 1024, 0, stream>>>(x, dWih, dWhh, db, attnW, outW,
                                                encH, decH, Pbuf, nullptr);
    projA_kernel<<<512, 256, 0, stream>>>(decH, attnW, attnb, Abuf);
    attn_kernel<false><<<512, 512, 0, stream>>>(encH, decH, Pbuf, Abuf, nullptr,
                                                vw, outW, outb, out);
  }
}